// Round 4
// baseline (423.537 us; speedup 1.0000x reference)
//
#include <hip/hip_runtime.h>
#include <cmath>

typedef unsigned int u32;
typedef unsigned long long u64;

#define NLEV 5
#define M_TOT 4900
#define NWORDS 77          // ceil(4900/64)
#define CSTRIDE 80         // cmat row stride in u64 words (640B)
#define CAP 65536          // candidate capacity per level
#define PAD_M 4928
#define NBLK 2999          // collect blocks (per-level partitioned)
#define LDSQ 1024          // per-block LDS candidate queue
#define NBIN 65536         // 16-bit histogram bins per level
#define TIE_CAP 4096
#define NBLK_CMAT 3003     // 77*78/2 triangular tiles
#define SCAN_PRE 96

__constant__ int   c_KLVL[5] = {1000,1000,1000,1000,900};
__constant__ int   c_LOFF[5] = {0,1000,2000,3000,4000};
__constant__ int   c_N4[5]   = {4608000,1152000,288000,72000,18000}; // float4s per level
__constant__ int   c_BB[6]   = {0,2250,2813,2954,2990,2999};         // block ranges per level
__constant__ float c_THR[5]  = {1.0f,0.65f,0.30f,-0.15f,-0.60f};

// ---- workspace layout (bytes) ----
constexpr size_t OFF_CNT   = 0;       // u32[8]
constexpr size_t OFF_FLAG  = 64;      // u32[8]
constexpr size_t OFF_KEPT  = 256;     // u64[96]
constexpr size_t OFF_GHIST = 4096;    // u32[5*NBIN]
constexpr size_t ZERO_BYTES= OFF_GHIST + (size_t)NLEV*NBIN*4;        // 1,314,816
constexpr size_t OFF_CAND  = ZERO_BYTES;                             // u32[5*CAP*2]
constexpr size_t OFF_KEY   = OFF_CAND + (size_t)NLEV*CAP*8;          // u64[PAD_M]
constexpr size_t OFF_RAWB  = OFF_KEY   + (size_t)PAD_M*8;            // float4
constexpr size_t OFF_OFFB  = OFF_RAWB  + (size_t)PAD_M*16;
constexpr size_t OFF_LAB   = OFF_OFFB  + (size_t)PAD_M*16;           // u32
constexpr size_t OFF_SVAL  = OFF_LAB   + (size_t)PAD_M*4;            // f32
constexpr size_t OFF_VALID = OFF_SVAL  + (size_t)PAD_M*4;            // u32
constexpr size_t OFF_SRAWB = OFF_VALID + (size_t)PAD_M*4;            // float4
constexpr size_t OFF_SOFFB = OFF_SRAWB + (size_t)PAD_M*16;
constexpr size_t OFF_SLAB  = OFF_SOFFB + (size_t)PAD_M*16;           // u32
constexpr size_t OFF_SSVAL = OFF_SLAB  + (size_t)PAD_M*4;            // f32
constexpr size_t OFF_SVALID= OFF_SSVAL + (size_t)PAD_M*4;            // u32
constexpr size_t OFF_CMAT  = (OFF_SVALID + (size_t)PAD_M*4 + 255) & ~(size_t)255;

__device__ __forceinline__ u32 okey(u32 u){
  return (u & 0x80000000u) ? ~u : (u | 0x80000000u);
}

__device__ __forceinline__ u32 lane_prior(u64 mask){
  return __builtin_amdgcn_mbcnt_hi((u32)(mask>>32),
         __builtin_amdgcn_mbcnt_lo((u32)mask, 0u));
}

// wave-aggregated LDS counter allocation; returns slot for take lanes,
// 0xFFFFFFFF otherwise. Must be executed wave-uniformly (no divergent exit).
__device__ __forceinline__ u32 wave_alloc(u32* ctr, bool take){
  u64 mask = __ballot(take);
  if (mask==0ull) return 0xFFFFFFFFu;
  u32 prior = lane_prior(mask);
  u32 total = (u32)__popcll(mask);
  int leader = __ffsll((unsigned long long)mask) - 1;
  u32 base = 0;
  if (take && prior==0u) base = atomicAdd(ctr, total);
  base = __shfl(base, leader, 64);
  return take ? (base + prior) : 0xFFFFFFFFu;
}

// ---------------- candidate collection (streaming pass over logits) --------
__global__ void __launch_bounds__(256)
k_collect(const float* __restrict__ a0, const float* __restrict__ a1,
          const float* __restrict__ a2, const float* __restrict__ a3,
          const float* __restrict__ a4,
          u32* __restrict__ cnt, u32* __restrict__ cand,
          u32* __restrict__ ghist, const u32* __restrict__ flags, int round)
{
  const int b = blockIdx.x;
  const int l = (b<c_BB[1])?0:(b<c_BB[2])?1:(b<c_BB[3])?2:(b<c_BB[4])?3:4;
  if (round!=0 && flags[l]==0u) return;
  const float* __restrict__ p = (l==0)?a0:(l==1)?a1:(l==2)?a2:(l==3)?a3:a4;
  const float T = c_THR[l] - 0.8f*(float)round;
  const int n4l = c_N4[l];
  const int lb  = b - c_BB[l];
  const int base4 = lb*2048 + (int)threadIdx.x;

  __shared__ u32 lcnt, gbase;
  __shared__ u32 lbitsA[LDSQ];
  __shared__ u32 lidxA[LDSQ];
  if (threadIdx.x==0) lcnt=0u;
  __syncthreads();

  float4 xs[8];
  int    qi[8];
#pragma unroll
  for (int u=0;u<8;u++){
    int q = base4 + u*256;
    int qc = (q < n4l) ? q : (n4l-1);
    qi[u] = q;
    xs[u] = *(const float4*)(p + (size_t)qc*4u);
  }
  u32* cdL = cand + (size_t)l*CAP*2u;
  u32* ghL = ghist + (u32)l*NBIN;
#pragma unroll
  for (int u=0;u<8;u++){
    if (qi[u] < n4l){
      float v[4]={xs[u].x,xs[u].y,xs[u].z,xs[u].w};
#pragma unroll
      for (int i=0;i<4;i++){
        if (v[i] > T){
          u32 bits = __float_as_uint(v[i]);
          atomicAdd(&ghL[okey(bits)>>16], 1u);
          u32 s = atomicAdd(&lcnt,1u);
          u32 idx  = (u32)(qi[u]*4+i);
          if (s < LDSQ){ lbitsA[s]=bits; lidxA[s]=idx; }
          else {
            u32 pp = atomicAdd(&cnt[l],1u);            // rare spill, exact count
            if (pp < CAP){ u32* d=cdL+(size_t)pp*2u; d[0]=bits; d[1]=idx; }
          }
        }
      }
    }
  }
  __syncthreads();
  if (threadIdx.x==0){
    u32 m = min(lcnt,(u32)LDSQ);
    gbase = (m>0u) ? atomicAdd(&cnt[l],m) : 0xFFFFFFFFu;
  }
  __syncthreads();
  u32 m = min(lcnt,(u32)LDSQ);
  for (u32 i=threadIdx.x;i<m;i+=256u){
    u32 pp = gbase + i;
    if (pp < CAP){ u32* d=cdL+(size_t)pp*2u; d[0]=lbitsA[i]; d[1]=lidxA[i]; }
  }
}

__global__ void __launch_bounds__(1024)
k_fbmark(u32* cnt, u32* flags, u32* ghist){
  __shared__ u32 f[5];
  if (threadIdx.x<5){
    u32 need=(cnt[threadIdx.x]<(u32)c_KLVL[threadIdx.x])?1u:0u;
    flags[threadIdx.x]=need; f[threadIdx.x]=need;
    if (need) cnt[threadIdx.x]=0u;
  }
  __syncthreads();
  for (int l=0;l<5;l++) if (f[l])
    for (u32 i=threadIdx.x;i<(u32)NBIN;i+=1024u) ghist[(u32)l*NBIN+i]=0u;
}

// ---------------- record emit helpers --------------------------------------
__device__ __forceinline__ void emit_record(int l, int slot, u32 lbits, u32 idx,
    const float4* __restrict__ boxp, u64* keyA, float4* rawbA, float4* offbA,
    u32* labA, float* svalA, u32* validA)
{
#pragma clang fp contract(off)
  float x = __uint_as_float(lbits);
  float s = (float)(1.0 / (1.0 + exp(-(double)x)));
  u32 valid = (s > 0.05f) ? 1u : 0u;
  u32 label = idx % 80u;
  u32 anchor = idx / 80u;
  float4 bx = boxp[anchor];
  float off = (float)label * 1281.0f;   // label * (IMG + 1)
  float4 ob;
  ob.x = bx.x + off; ob.y = bx.y + off; ob.z = bx.z + off; ob.w = bx.w + off;
  u32 pos = ((u32)l << 25) | idx;
  u32 khi = valid ? okey(lbits) : 0u;
  int g = c_LOFF[l] + slot;
  keyA[g]  = ((u64)khi << 32) | (u64)(u32)(~pos);
  rawbA[g] = bx; offbA[g] = ob; labA[g] = label;
  svalA[g] = valid ? s : 0.0f; validA[g] = valid;
}

__device__ __forceinline__ void emit_dummy(int l, int slot,
    u64* keyA, float4* rawbA, float4* offbA, u32* labA, float* svalA, u32* validA)
{
  u32 pos = ((u32)l<<25) | (0x1FFFFFFu - (u32)slot);  // unique, beyond real idx
  int g = c_LOFF[l]+slot;
  float4 z; z.x=z.y=z.z=z.w=0.0f;
  keyA[g]=(u64)(u32)(~pos);
  rawbA[g]=z; offbA[g]=z; labA[g]=0u; svalA[g]=0.0f; validA[g]=0u;
}

// ------ per-level exact top-k via 16-bit histogram cutoff + tie refine -----
__global__ void __launch_bounds__(1024)
k_select(const u32* __restrict__ cnt, const u32* __restrict__ cand,
         const u32* __restrict__ ghist,
         const float4* b0, const float4* b1, const float4* b2,
         const float4* b3, const float4* b4,
         u64* keyA, float4* rawbA, float4* offbA,
         u32* labA, float* svalA, u32* validA)
{
  const int l = blockIdx.x;
  const float4* boxp = (l==0)?b0:(l==1)?b1:(l==2)?b2:(l==3)?b3:b4;
  const u32* cd = cand + (size_t)l*CAP*2u;
  const int k = c_KLVL[l];
  const u32 count = min(cnt[l], (u32)CAP);
  const u32* gh = ghist + (u32)l*NBIN;

  __shared__ u32 sufw[16];
  __shared__ u32 c0_s, kk_s;
  __shared__ u32 emit_s, ntie_s;
  __shared__ u32 tb[TIE_CAP], ti[TIE_CAP];

  const u32 tid = threadIdx.x;
  const u32 lane = tid & 63u;
  const u32 wave = tid >> 6;
  if (tid==0){ emit_s=0u; ntie_s=0u; c0_s=0u; kk_s=0u; }
  __syncthreads();

  if (count > (u32)k){
    // --- suffix-scan the 65536-bin histogram to find cutoff c0, kk ---
    u32 base = tid*64u;
    u32 ls = 0u;
    for (int b2_=0;b2_<64;b2_++) ls += gh[base+(u32)b2_];
    u32 x = ls;
#pragma unroll
    for (int off=1; off<64; off<<=1){
      u32 y = __shfl_down(x, off, 64);
      if (lane + (u32)off < 64u) x += y;
    }                                   // x = sum over lanes >= lane in wave
    if (lane==0u) sufw[wave]=x;
    __syncthreads();
    u32 wsuf=0u;
    for (u32 w=wave+1u;w<16u;w++) wsuf += sufw[w];
    u32 suffix_after = wsuf + (x - ls); // strictly above my chunk
    if (suffix_after < (u32)k && (u32)k <= suffix_after + ls){
      u32 run = suffix_after;
      for (int b2_=63;b2_>=0;b2_--){
        u32 h = gh[base+(u32)b2_];
        run += h;
        if (run >= (u32)k){ c0_s = base+(u32)b2_; kk_s = (u32)k - (run - h); break; }
      }
    }
    __syncthreads();
    const u32 c0 = c0_s, kk = kk_s;

    // --- single pass: emit definite winners, stash tie-bin in LDS ---
    u32 iters = (count + 1023u)/1024u;
    for (u32 it=0; it<iters; it++){
      u32 i = it*1024u + tid;
      bool in = i < count;
      u32 bits = in ? cd[2*(size_t)i] : 0u;
      u32 idx  = in ? cd[2*(size_t)i+1] : 0u;
      u32 key  = okey(bits);
      u32 h    = key>>16;
      bool hi  = in && (h > c0);
      bool tie = in && (h == c0);
      u32 s = wave_alloc(&emit_s, hi);
      if (hi && s < (u32)k)
        emit_record(l,(int)s,bits,idx,boxp,keyA,rawbA,offbA,labA,svalA,validA);
      u32 t = wave_alloc(&ntie_s, tie);
      if (tie && t < (u32)TIE_CAP){ tb[t]=bits; ti[t]=idx; }
    }
    __syncthreads();

    // --- exact refine within tie bin (full key desc, idx asc) ---
    u32 nt = min(ntie_s,(u32)TIE_CAP);
    for (u32 e=tid;e<nt;e+=1024u){
      u32 mk = okey(tb[e]); u32 mi = ti[e];
      u32 r=0u;
      for (u32 e2=0;e2<nt;e2++){
        u32 k2 = okey(tb[e2]);
        r += (k2>mk || (k2==mk && ti[e2]<mi)) ? 1u : 0u;
      }
      if (r < kk){
        u32 s = atomicAdd(&emit_s,1u);
        if (s < (u32)k)
          emit_record(l,(int)s,tb[e],mi,boxp,keyA,rawbA,offbA,labA,svalA,validA);
      }
    }
  } else {
    // fallback-failed path: emit everything we have
    u32 iters = (count + 1023u)/1024u;
    for (u32 it=0; it<iters; it++){
      u32 i = it*1024u + tid;
      bool in = i < count;
      u32 bits = in ? cd[2*(size_t)i] : 0u;
      u32 idx  = in ? cd[2*(size_t)i+1] : 0u;
      u32 s = wave_alloc(&emit_s, in);
      if (in && s < (u32)k)
        emit_record(l,(int)s,bits,idx,boxp,keyA,rawbA,offbA,labA,svalA,validA);
    }
  }
  __syncthreads();
  u32 em = min(emit_s,(u32)k);
  for (u32 i=em+tid;i<(u32)k;i+=1024u)
    emit_dummy(l,(int)i,keyA,rawbA,offbA,labA,svalA,validA);
}

// ------- global sort via rank-by-counting (unique keys) + fused gather -----
__global__ void __launch_bounds__(256)
k_rank(const u64* __restrict__ keyA,
       const float4* __restrict__ rawbA, const float4* __restrict__ offbA,
       const u32* __restrict__ labA, const float* __restrict__ svalA,
       const u32* __restrict__ validA,
       float4* srawb, float4* soffb, u32* slab, float* ssval, u32* svalid)
{
  __shared__ u64 sk[M_TOT];
  __shared__ u32 part[3][64];
  for (int i=threadIdx.x;i<M_TOT;i+=256) sk[i]=keyA[i];
  __syncthreads();
  int lane = threadIdx.x & 63;
  int wave = threadIdx.x >> 6;
  int i = blockIdx.x*64 + lane;
  u64 mk = sk[(i<M_TOT)?i:0];
  int j0 = wave*1225;
  u32 r=0;
#pragma unroll 5
  for (int j=j0;j<j0+1225;j++) r += (sk[j]>mk)?1u:0u;
  if (wave) part[wave-1][lane]=r;
  __syncthreads();
  if (wave==0 && i<M_TOT){
    r += part[0][lane]+part[1][lane]+part[2][lane];
    srawb[r]=rawbA[i]; soffb[r]=offbA[i]; slab[r]=labA[i];
    ssval[r]=svalA[i]; svalid[r]=validA[i];
  }
}

// ------- predecessor bitmask matrix: triangular 64x64 tiles ----------------
__global__ void __launch_bounds__(256)
k_cmat(const float4* __restrict__ soffb, u64* __restrict__ cmat)
{
#pragma clang fp contract(off)
  int bi = blockIdx.x;
  int jt = (int)((sqrtf(8.0f*(float)bi+1.0f)-1.0f)*0.5f);
  while ((jt+1)*(jt+2)/2 <= bi) jt++;
  while (jt*(jt+1)/2 > bi) jt--;
  int wt = bi - jt*(jt+1)/2;

  __shared__ float rx[64],ry[64],rz[64],rw[64],ra[64];
  __shared__ float cx[64],cy[64],cz[64],cw[64],cae[64];
  int tid = threadIdx.x;
  if (tid<64){
    float4 b = soffb[wt*64+tid];
    rx[tid]=b.x; ry[tid]=b.y; rz[tid]=b.z; rw[tid]=b.w;
    ra[tid]=fmaxf(b.z-b.x,0.0f)*fmaxf(b.w-b.y,0.0f);
  } else if (tid<128){
    int c=tid-64;
    float4 b = soffb[jt*64+c];
    cx[c]=b.x; cy[c]=b.y; cz[c]=b.z; cw[c]=b.w;
    cae[c]=fmaxf(b.z-b.x,0.0f)*fmaxf(b.w-b.y,0.0f);
  }
  __syncthreads();
  int lane = tid & 63;
  int wave = tid >> 6;
  int rowg = wt*64 + lane;
  float bx=rx[lane], by=ry[lane], bz=rz[lane], bw=rw[lane], bar=ra[lane];
  for (int cc=wave*16; cc<wave*16+16; cc++){
    int jg = jt*64 + cc;
    if (jg >= M_TOT) continue;          // uniform across wave
    float jx=cx[cc], jy=cy[cc], jz=cz[cc], jw=cw[cc], jar=cae[cc];
    float ltx=fmaxf(bx,jx), lty=fmaxf(by,jy);
    float rbx=fminf(bz,jz), rby=fminf(bw,jw);
    float wx=fmaxf(rbx-ltx,0.0f), wy=fmaxf(rby-lty,0.0f);
    float inter=wx*wy;
    float iou = inter/(bar+jar-inter+1e-9f);
    bool bit = (rowg < jg) && (iou > 0.6f);
    u64 word = __ballot(bit);
    if (lane==0) cmat[(size_t)jg*CSTRIDE + (size_t)wt] = word;
  }
}

// ------- greedy resolution per class (cmat bits are same-class only) -------
__global__ void __launch_bounds__(64)
k_scan(const u64* __restrict__ cmat, const u32* __restrict__ svalid,
       const u32* __restrict__ slab, u64* __restrict__ kept)
{
  const u32 c = blockIdx.x;             // class id 0..79
  __shared__ unsigned short list[512];  // j | valid<<15, ascending
  __shared__ u64 lcol[SCAN_PRE][80];
  int lane = threadIdx.x;
  u32 nc = 0u;
  for (int w=0; w<77; w++){
    int j = w*64+lane;
    bool inr = (j < M_TOT);
    u32 lab = inr ? slab[j] : 0xFFFFFFFFu;
    u32 sv  = inr ? svalid[j] : 0u;
    bool mine = inr && (lab == c);
    u64 mask = __ballot(mine);
    if (mask){
      u32 prior = lane_prior(mask);
      u32 slot = nc + prior;
      if (mine && slot < 512u)
        list[slot] = (unsigned short)((u32)j | ((sv&1u)<<15));
      nc += (u32)__popcll(mask);
    }
  }
  nc = min(nc, 512u);
  if (nc==0u) return;

  // preload columns (diag-masked) into LDS, fully pipelined
  u32 npre = min(nc,(u32)SCAN_PRE);
  u32 tot = npre*80u;
  for (u32 x=(u32)lane; x<tot; x+=64u){
    u32 t = x/80u, w = x%80u;
    u32 j = (u32)list[t] & 0x1FFFu;
    u32 wmax = j>>6;
    u64 v = (w <= wmax) ? cmat[(size_t)j*CSTRIDE + w] : 0ull;
    lcol[t][w] = v;
  }
  // single wave: LDS writes visible in program order; ballot keeps lockstep
  u64 kw0=0ull, kw1=0ull;
  for (u32 t=0;t<nc;t++){
    u32 e = (u32)list[t];
    u32 j = e & 0x1FFFu;
    u32 v = (e>>15)&1u;
    u64 c0,c1;
    if (t < npre){
      c0 = lcol[t][lane];
      c1 = (lane<13) ? lcol[t][64+lane] : 0ull;
    } else {
      const u64* cp = cmat + (size_t)j*CSTRIDE;
      u32 wmax = j>>6;
      c0 = ((u32)lane <= wmax) ? cp[lane] : 0ull;
      c1 = ((u32)(lane+64) <= wmax) ? cp[lane+64] : 0ull;
    }
    bool hit = ((c0&kw0)|(c1&kw1)) != 0ull;
    bool any = __ballot(hit) != 0ull;
    if (!any && v){
      u32 w=j>>6, b=j&63u;
      if ((u32)lane==w)        kw0 |= (1ull<<b);
      if ((u32)lane==(w-64u))  kw1 |= (1ull<<b);
    }
  }
  if (kw0) atomicOr(&kept[lane], kw0);
  if (lane<13 && kw1) atomicOr(&kept[64+lane], kw1);
}

// ---------------- final outputs -------------------------------------------
__global__ void k_out(const u64* __restrict__ kept, const float4* __restrict__ srawb,
                      const float* __restrict__ ssval, const u32* __restrict__ slab,
                      float* __restrict__ out)
{
  int t=blockIdx.x*blockDim.x+threadIdx.x;
  if (t<M_TOT){
    u32 kb=(u32)((kept[t>>6]>>(t&63))&1ull);
    float kf=kb?1.0f:0.0f;
    float4 b=srawb[t];
    out[4*t+0]=fminf(fmaxf(b.x/1280.0f,0.0f),1.0f)*kf;
    out[4*t+1]=fminf(fmaxf(b.y/1280.0f,0.0f),1.0f)*kf;
    out[4*t+2]=fminf(fmaxf(b.z/1280.0f,0.0f),1.0f)*kf;
    out[4*t+3]=fminf(fmaxf(b.w/1280.0f,0.0f),1.0f)*kf;
    out[19600+t]=ssval[t]*kf;
    out[24500+t]=(float)slab[t];
    out[29400+t]=kf;
  }
}

// ---------------- host ----------------------------------------------------
extern "C" void kernel_launch(void* const* d_in, const int* in_sizes, int n_in,
                              void* d_out, int out_size, void* d_ws, size_t ws_size,
                              hipStream_t stream)
{
  const float* cls[5]={nullptr,nullptr,nullptr,nullptr,nullptr};
  const float* box[5]={nullptr,nullptr,nullptr,nullptr,nullptr};
  static const int clsEl[5]={18432000,4608000,1152000,288000,72000};
  static const int boxEl[5]={921600,230400,57600,14400,3600};
  for (int i=0;i<n_in;i++){
    int sz=in_sizes[i];
    bool done=false;
    for (int l=0;l<5 && !done;l++){
      if (sz==clsEl[l] && !cls[l]){ cls[l]=(const float*)d_in[i]; done=true; }
      else if (sz==boxEl[l] && !box[l]){ box[l]=(const float*)d_in[i]; done=true; }
    }
  }
  unsigned char* ws=(unsigned char*)d_ws;
  u32* cnt   = (u32*)(ws+OFF_CNT);
  u32* flags = (u32*)(ws+OFF_FLAG);
  u64* kept  = (u64*)(ws+OFF_KEPT);
  u32* ghist = (u32*)(ws+OFF_GHIST);
  u32* cand  = (u32*)(ws+OFF_CAND);
  u64* keyA  = (u64*)(ws+OFF_KEY);
  float4* rawbA=(float4*)(ws+OFF_RAWB);
  float4* offbA=(float4*)(ws+OFF_OFFB);
  u32* labA  = (u32*)(ws+OFF_LAB);
  float* svalA=(float*)(ws+OFF_SVAL);
  u32* validA=(u32*)(ws+OFF_VALID);
  float4* srawb=(float4*)(ws+OFF_SRAWB);
  float4* soffb=(float4*)(ws+OFF_SOFFB);
  u32* slab  = (u32*)(ws+OFF_SLAB);
  float* ssval=(float*)(ws+OFF_SSVAL);
  u32* svalid=(u32*)(ws+OFF_SVALID);
  u64* cmat  = (u64*)(ws+OFF_CMAT);
  float* out = (float*)d_out;

  hipMemsetAsync(ws, 0, ZERO_BYTES, stream);

  k_collect<<<dim3(NBLK),dim3(256),0,stream>>>(cls[0],cls[1],cls[2],cls[3],cls[4],cnt,cand,ghist,flags,0);
  k_fbmark <<<dim3(1),dim3(1024),0,stream>>>(cnt,flags,ghist);
  k_collect<<<dim3(NBLK),dim3(256),0,stream>>>(cls[0],cls[1],cls[2],cls[3],cls[4],cnt,cand,ghist,flags,1);
  k_fbmark <<<dim3(1),dim3(1024),0,stream>>>(cnt,flags,ghist);
  k_collect<<<dim3(NBLK),dim3(256),0,stream>>>(cls[0],cls[1],cls[2],cls[3],cls[4],cnt,cand,ghist,flags,2);

  k_select<<<dim3(5),dim3(1024),0,stream>>>(cnt,cand,ghist,
      (const float4*)box[0],(const float4*)box[1],(const float4*)box[2],
      (const float4*)box[3],(const float4*)box[4],
      keyA,rawbA,offbA,labA,svalA,validA);

  k_rank  <<<dim3(77),dim3(256),0,stream>>>(keyA,rawbA,offbA,labA,svalA,validA,
                                            srawb,soffb,slab,ssval,svalid);
  k_cmat  <<<dim3(NBLK_CMAT),dim3(256),0,stream>>>(soffb,cmat);
  k_scan  <<<dim3(80),dim3(64),0,stream>>>(cmat,svalid,slab,kept);
  k_out   <<<dim3(20),dim3(256),0,stream>>>(kept,srawb,ssval,slab,out);
}

// Round 5
// 340.733 us; speedup vs baseline: 1.2430x; 1.2430x over previous
//
#include <hip/hip_runtime.h>
#include <cmath>

typedef unsigned int u32;
typedef unsigned long long u64;

#define NLEV 5
#define M_TOT 4900
#define NWORDS 77          // ceil(4900/64)
#define CSTRIDE 80         // cmat row stride in u64 words (640B)
#define CAP 65536          // candidate capacity per level
#define PAD_M 4928
#define NBLK 1501          // collect blocks (per-level partitioned, 64 floats/thread)
#define LDSQ 1024          // per-block LDS candidate queue
#define TIE_CAP 2048
#define NBLK_CMAT 3003     // 77*78/2 triangular tiles
#define HBINS 4096         // 12-bit histogram in k_select LDS

__constant__ int   c_KLVL[5] = {1000,1000,1000,1000,900};
__constant__ int   c_LOFF[5] = {0,1000,2000,3000,4000};
__constant__ int   c_N4[5]   = {4608000,1152000,288000,72000,18000}; // float4s per level
__constant__ int   c_BB[6]   = {0,1125,1407,1478,1496,1501};         // block ranges per level
__constant__ float c_THR[5]  = {1.0f,0.65f,0.30f,-0.15f,-0.60f};

// ---- workspace layout (bytes) ----
constexpr size_t OFF_CNT   = 0;       // u32[8]
constexpr size_t OFF_FLAG  = 64;      // u32[8]
constexpr size_t OFF_KEPT  = 256;     // u64[96]
constexpr size_t ZERO_BYTES= 4096;
constexpr size_t OFF_CAND  = ZERO_BYTES;                             // u32[5*CAP*2]
constexpr size_t OFF_KEY   = OFF_CAND + (size_t)NLEV*CAP*8;          // u64[PAD_M]
constexpr size_t OFF_RAWB  = OFF_KEY   + (size_t)PAD_M*8;            // float4
constexpr size_t OFF_OFFB  = OFF_RAWB  + (size_t)PAD_M*16;
constexpr size_t OFF_LAB   = OFF_OFFB  + (size_t)PAD_M*16;           // u32
constexpr size_t OFF_SVAL  = OFF_LAB   + (size_t)PAD_M*4;            // f32
constexpr size_t OFF_VALID = OFF_SVAL  + (size_t)PAD_M*4;            // u32
constexpr size_t OFF_SRAWB = OFF_VALID + (size_t)PAD_M*4;            // float4
constexpr size_t OFF_SOFFB = OFF_SRAWB + (size_t)PAD_M*16;
constexpr size_t OFF_SLAB  = OFF_SOFFB + (size_t)PAD_M*16;           // u32
constexpr size_t OFF_SSVAL = OFF_SLAB  + (size_t)PAD_M*4;            // f32
constexpr size_t OFF_SVALID= OFF_SSVAL + (size_t)PAD_M*4;            // u32
constexpr size_t OFF_CMAT  = (OFF_SVALID + (size_t)PAD_M*4 + 255) & ~(size_t)255;

__device__ __forceinline__ u32 okey(u32 u){
  return (u & 0x80000000u) ? ~u : (u | 0x80000000u);
}

__device__ __forceinline__ u32 lane_prior(u64 mask){
  return __builtin_amdgcn_mbcnt_hi((u32)(mask>>32),
         __builtin_amdgcn_mbcnt_lo((u32)mask, 0u));
}

// wave-aggregated LDS counter allocation; wave-uniform execution required.
__device__ __forceinline__ u32 wave_alloc(u32* ctr, bool take){
  u64 mask = __ballot(take);
  if (mask==0ull) return 0xFFFFFFFFu;
  u32 prior = lane_prior(mask);
  u32 total = (u32)__popcll(mask);
  int leader = __ffsll((unsigned long long)mask) - 1;
  u32 base = 0;
  if (take && prior==0u) base = atomicAdd(ctr, total);
  base = __shfl(base, leader, 64);
  return take ? (base + prior) : 0xFFFFFFFFu;
}

// ---------------- candidate collection (pure streaming pass) --------------
__global__ void __launch_bounds__(256)
k_collect(const float* __restrict__ a0, const float* __restrict__ a1,
          const float* __restrict__ a2, const float* __restrict__ a3,
          const float* __restrict__ a4,
          u32* __restrict__ cnt, u32* __restrict__ cand,
          const u32* __restrict__ flags, int round)
{
  const int b = blockIdx.x;
  const int l = (b<c_BB[1])?0:(b<c_BB[2])?1:(b<c_BB[3])?2:(b<c_BB[4])?3:4;
  if (round!=0 && flags[l]==0u) return;
  const float* __restrict__ p = (l==0)?a0:(l==1)?a1:(l==2)?a2:(l==3)?a3:a4;
  const float T = c_THR[l] - 0.8f*(float)round;
  const int n4l = c_N4[l];
  const int lb  = b - c_BB[l];
  const int base4 = lb*4096 + (int)threadIdx.x;

  __shared__ u32 lcnt, gbase;
  __shared__ u32 lbitsA[LDSQ];
  __shared__ u32 lidxA[LDSQ];
  if (threadIdx.x==0) lcnt=0u;
  __syncthreads();

  float4 xs[16];
#pragma unroll
  for (int u=0;u<16;u++){
    int q = base4 + u*256;
    int qc = (q < n4l) ? q : (n4l-1);
    xs[u] = *(const float4*)(p + (size_t)qc*4u);
  }
  u32* cdL = cand + (size_t)l*CAP*2u;
#pragma unroll
  for (int u=0;u<16;u++){
    int q = base4 + u*256;
    if (q < n4l){
      float v[4]={xs[u].x,xs[u].y,xs[u].z,xs[u].w};
#pragma unroll
      for (int i=0;i<4;i++){
        if (v[i] > T){
          u32 s = atomicAdd(&lcnt,1u);
          u32 bits = __float_as_uint(v[i]);
          u32 idx  = (u32)(q*4+i);
          if (s < LDSQ){ lbitsA[s]=bits; lidxA[s]=idx; }
          else {
            u32 pp = atomicAdd(&cnt[l],1u);            // rare spill, exact count
            if (pp < CAP){ u32* d=cdL+(size_t)pp*2u; d[0]=bits; d[1]=idx; }
          }
        }
      }
    }
  }
  __syncthreads();
  if (threadIdx.x==0){
    u32 m = min(lcnt,(u32)LDSQ);
    gbase = (m>0u) ? atomicAdd(&cnt[l],m) : 0xFFFFFFFFu;
  }
  __syncthreads();
  u32 m = min(lcnt,(u32)LDSQ);
  for (u32 i=threadIdx.x;i<m;i+=256u){
    u32 pp = gbase + i;
    if (pp < CAP){ u32* d=cdL+(size_t)pp*2u; d[0]=lbitsA[i]; d[1]=lidxA[i]; }
  }
}

__global__ void k_fbmark(u32* cnt, u32* flags){
  int t=threadIdx.x;
  if (t<5){
    u32 need=(cnt[t]<(u32)c_KLVL[t])?1u:0u;
    flags[t]=need;
    if (need) cnt[t]=0u;
  }
}

// ---------------- record emit helpers --------------------------------------
__device__ __forceinline__ void emit_record(int l, int slot, u32 lbits, u32 idx,
    const float4* __restrict__ boxp, u64* keyA, float4* rawbA, float4* offbA,
    u32* labA, float* svalA, u32* validA)
{
#pragma clang fp contract(off)
  float x = __uint_as_float(lbits);
  float s = (float)(1.0 / (1.0 + exp(-(double)x)));
  u32 valid = (s > 0.05f) ? 1u : 0u;
  u32 label = idx % 80u;
  u32 anchor = idx / 80u;
  float4 bx = boxp[anchor];
  float off = (float)label * 1281.0f;   // label * (IMG + 1)
  float4 ob;
  ob.x = bx.x + off; ob.y = bx.y + off; ob.z = bx.z + off; ob.w = bx.w + off;
  u32 pos = ((u32)l << 25) | idx;
  u32 khi = valid ? okey(lbits) : 0u;
  int g = c_LOFF[l] + slot;
  keyA[g]  = ((u64)khi << 32) | (u64)(u32)(~pos);
  rawbA[g] = bx; offbA[g] = ob; labA[g] = label;
  svalA[g] = valid ? s : 0.0f; validA[g] = valid;
}

__device__ __forceinline__ void emit_dummy(int l, int slot,
    u64* keyA, float4* rawbA, float4* offbA, u32* labA, float* svalA, u32* validA)
{
  u32 pos = ((u32)l<<25) | (0x1FFFFFFu - (u32)slot);  // unique, beyond real idx
  int g = c_LOFF[l]+slot;
  float4 z; z.x=z.y=z.z=z.w=0.0f;
  keyA[g]=(u64)(u32)(~pos);
  rawbA[g]=z; offbA[g]=z; labA[g]=0u; svalA[g]=0.0f; validA[g]=0u;
}

// --- per-level exact top-k via 12-bit LDS histogram cutoff + tie refine ----
__global__ void __launch_bounds__(1024)
k_select(const u32* __restrict__ cnt, const u32* __restrict__ cand,
         const float4* b0, const float4* b1, const float4* b2,
         const float4* b3, const float4* b4,
         u64* keyA, float4* rawbA, float4* offbA,
         u32* labA, float* svalA, u32* validA)
{
  const int l = blockIdx.x;
  const float4* boxp = (l==0)?b0:(l==1)?b1:(l==2)?b2:(l==3)?b3:b4;
  const u32* cd = cand + (size_t)l*CAP*2u;
  const int k = c_KLVL[l];
  const u32 count = min(cnt[l], (u32)CAP);

  __shared__ u32 lhist[4][HBINS];      // 4 replicas to cut same-address chains
  __shared__ u32 sufw[16];
  __shared__ u32 c0_s, kk_s;
  __shared__ u32 emit_s, ntie_s;
  __shared__ u32 tb[TIE_CAP], ti[TIE_CAP];

  const u32 tid = threadIdx.x;
  const u32 lane = tid & 63u;
  const u32 wave = tid >> 6;
  if (tid==0){ emit_s=0u; ntie_s=0u; c0_s=0u; kk_s=0u; }
  for (u32 i=tid;i<4u*HBINS;i+=1024u) ((u32*)lhist)[i]=0u;
  __syncthreads();

  if (count > (u32)k){
    // --- pass A: 12-bit histogram of okey ---
    const u32 rep = wave & 3u;
    for (u32 i=tid;i<count;i+=1024u)
      atomicAdd(&lhist[rep][okey(cd[2*(size_t)i])>>20], 1u);
    __syncthreads();
    // merge replicas: thread owns bins [tid*4, tid*4+4)
    u32 base = tid*4u;
    u32 hb[4]; u32 ls=0u;
#pragma unroll
    for (int b2_=0;b2_<4;b2_++){
      u32 h = lhist[0][base+(u32)b2_]+lhist[1][base+(u32)b2_]
            + lhist[2][base+(u32)b2_]+lhist[3][base+(u32)b2_];
      hb[b2_]=h; ls+=h;
    }
    // suffix-scan across threads (descending bin index)
    u32 x = ls;
#pragma unroll
    for (int off=1; off<64; off<<=1){
      u32 y = __shfl_down(x, off, 64);
      if (lane + (u32)off < 64u) x += y;
    }
    if (lane==0u) sufw[wave]=x;
    __syncthreads();
    u32 wsuf=0u;
    for (u32 w=wave+1u;w<16u;w++) wsuf += sufw[w];
    u32 suffix_after = wsuf + (x - ls);  // strictly above my 4-bin chunk
    if (suffix_after < (u32)k && (u32)k <= suffix_after + ls){
      u32 run = suffix_after;
      for (int b2_=3;b2_>=0;b2_--){
        u32 h = hb[b2_];
        run += h;
        if (run >= (u32)k){ c0_s = base+(u32)b2_; kk_s = (u32)k - (run - h); break; }
      }
    }
    __syncthreads();
    const u32 c0 = c0_s, kk = kk_s;

    // --- pass B: emit definite winners, stash tie-bin ---
    u32 iters = (count + 1023u)/1024u;
    for (u32 it=0; it<iters; it++){
      u32 i = it*1024u + tid;
      bool in = i < count;
      u32 bits = in ? cd[2*(size_t)i] : 0u;
      u32 idx  = in ? cd[2*(size_t)i+1] : 0u;
      u32 h    = okey(bits)>>20;
      bool hi  = in && (h > c0);
      bool tie = in && (h == c0);
      u32 s = wave_alloc(&emit_s, hi);
      if (hi && s < (u32)k)
        emit_record(l,(int)s,bits,idx,boxp,keyA,rawbA,offbA,labA,svalA,validA);
      u32 t = wave_alloc(&ntie_s, tie);
      if (tie && t < (u32)TIE_CAP){ tb[t]=bits; ti[t]=idx; }
    }
    __syncthreads();

    // --- exact refine within tie bin (full key desc, idx asc) ---
    u32 nt = min(ntie_s,(u32)TIE_CAP);
    for (u32 e=tid;e<nt;e+=1024u){
      u32 mk = okey(tb[e]); u32 mi = ti[e];
      u32 r=0u;
      for (u32 e2=0;e2<nt;e2++){
        u32 k2 = okey(tb[e2]);
        r += (k2>mk || (k2==mk && ti[e2]<mi)) ? 1u : 0u;
      }
      if (r < kk){
        u32 s = atomicAdd(&emit_s,1u);
        if (s < (u32)k)
          emit_record(l,(int)s,tb[e],mi,boxp,keyA,rawbA,offbA,labA,svalA,validA);
      }
    }
  } else {
    u32 iters = (count + 1023u)/1024u;
    for (u32 it=0; it<iters; it++){
      u32 i = it*1024u + tid;
      bool in = i < count;
      u32 bits = in ? cd[2*(size_t)i] : 0u;
      u32 idx  = in ? cd[2*(size_t)i+1] : 0u;
      u32 s = wave_alloc(&emit_s, in);
      if (in && s < (u32)k)
        emit_record(l,(int)s,bits,idx,boxp,keyA,rawbA,offbA,labA,svalA,validA);
    }
  }
  __syncthreads();
  u32 em = min(emit_s,(u32)k);
  for (u32 i=em+tid;i<(u32)k;i+=1024u)
    emit_dummy(l,(int)i,keyA,rawbA,offbA,labA,svalA,validA);
}

// ------- global sort via rank-by-counting (unique keys) + fused gather -----
__global__ void __launch_bounds__(256)
k_rank(const u64* __restrict__ keyA,
       const float4* __restrict__ rawbA, const float4* __restrict__ offbA,
       const u32* __restrict__ labA, const float* __restrict__ svalA,
       const u32* __restrict__ validA,
       float4* srawb, float4* soffb, u32* slab, float* ssval, u32* svalid)
{
  __shared__ u64 sk[M_TOT];
  __shared__ u32 part[3][64];
  for (int i=threadIdx.x;i<M_TOT;i+=256) sk[i]=keyA[i];
  __syncthreads();
  int lane = threadIdx.x & 63;
  int wave = threadIdx.x >> 6;
  int i = blockIdx.x*64 + lane;
  u64 mk = sk[(i<M_TOT)?i:0];
  int j0 = wave*1225;
  u32 r=0;
#pragma unroll 5
  for (int j=j0;j<j0+1225;j++) r += (sk[j]>mk)?1u:0u;
  if (wave) part[wave-1][lane]=r;
  __syncthreads();
  if (wave==0 && i<M_TOT){
    r += part[0][lane]+part[1][lane]+part[2][lane];
    srawb[r]=rawbA[i]; soffb[r]=offbA[i]; slab[r]=labA[i];
    ssval[r]=svalA[i]; svalid[r]=validA[i];
  }
}

// ------- predecessor bitmask matrix: triangular 64x64 tiles ----------------
__global__ void __launch_bounds__(256)
k_cmat(const float4* __restrict__ soffb, u64* __restrict__ cmat)
{
#pragma clang fp contract(off)
  int bi = blockIdx.x;
  int jt = (int)((sqrtf(8.0f*(float)bi+1.0f)-1.0f)*0.5f);
  while ((jt+1)*(jt+2)/2 <= bi) jt++;
  while (jt*(jt+1)/2 > bi) jt--;
  int wt = bi - jt*(jt+1)/2;

  __shared__ float rx[64],ry[64],rz[64],rw[64],ra[64];
  __shared__ float cx[64],cy[64],cz[64],cw[64],cae[64];
  int tid = threadIdx.x;
  if (tid<64){
    float4 b = soffb[wt*64+tid];
    rx[tid]=b.x; ry[tid]=b.y; rz[tid]=b.z; rw[tid]=b.w;
    ra[tid]=fmaxf(b.z-b.x,0.0f)*fmaxf(b.w-b.y,0.0f);
  } else if (tid<128){
    int c=tid-64;
    float4 b = soffb[jt*64+c];
    cx[c]=b.x; cy[c]=b.y; cz[c]=b.z; cw[c]=b.w;
    cae[c]=fmaxf(b.z-b.x,0.0f)*fmaxf(b.w-b.y,0.0f);
  }
  __syncthreads();
  int lane = tid & 63;
  int wave = tid >> 6;
  int rowg = wt*64 + lane;
  float bx=rx[lane], by=ry[lane], bz=rz[lane], bw=rw[lane], bar=ra[lane];
  for (int cc=wave*16; cc<wave*16+16; cc++){
    int jg = jt*64 + cc;
    if (jg >= M_TOT) continue;          // uniform across wave
    float jx=cx[cc], jy=cy[cc], jz=cz[cc], jw=cw[cc], jar=cae[cc];
    float ltx=fmaxf(bx,jx), lty=fmaxf(by,jy);
    float rbx=fminf(bz,jz), rby=fminf(bw,jw);
    float wx=fmaxf(rbx-ltx,0.0f), wy=fmaxf(rby-lty,0.0f);
    float inter=wx*wy;
    float iou = inter/(bar+jar-inter+1e-9f);
    bool bit = (rowg < jg) && (iou > 0.6f);
    u64 word = __ballot(bit);
    if (lane==0) cmat[(size_t)jg*CSTRIDE + (size_t)wt] = word;
  }
}

// ------- greedy resolution per class (cmat bits are same-class only) -------
__global__ void __launch_bounds__(64)
k_scan(const u64* __restrict__ cmat, const u32* __restrict__ svalid,
       const u32* __restrict__ slab, u64* __restrict__ kept)
{
  const u32 c = blockIdx.x;             // class id 0..79
  __shared__ unsigned short list[512];  // j | valid<<15, ascending
  int lane = threadIdx.x;
  u32 nc = 0u;
  for (int w=0; w<77; w++){
    int j = w*64+lane;
    bool inr = (j < M_TOT);
    u32 lab = inr ? slab[j] : 0xFFFFFFFFu;
    u32 sv  = inr ? svalid[j] : 0u;
    bool mine = inr && (lab == c);
    u64 mask = __ballot(mine);
    if (mask){
      u32 prior = lane_prior(mask);
      u32 slot = nc + prior;
      if (mine && slot < 512u)
        list[slot] = (unsigned short)((u32)j | ((sv&1u)<<15));
      nc += (u32)__popcll(mask);
    }
  }
  nc = min(nc, 512u);
  if (nc==0u) return;

  // depth-4 register prefetch ring over diagonal-masked columns
  u64 ca[4], cb[4]; u32 vv[4];
#pragma unroll
  for (int i=0;i<4;i++){
    ca[i]=0ull; cb[i]=0ull; vv[i]=0u;
    if ((u32)i<nc){
      u32 e=(u32)list[i]; u32 j=e&0x1FFFu; u32 wmax=j>>6;
      const u64* cp=cmat+(size_t)j*CSTRIDE;
      ca[i]=((u32)lane<=wmax)?cp[lane]:0ull;
      cb[i]=((u32)(lane+64)<=wmax)?cp[lane+64]:0ull;
      vv[i]=(e>>15)&1u;
    }
  }
  u64 kw0=0ull, kw1=0ull;
  for (u32 base=0; base<nc; base+=4){
#pragma unroll
    for (int i=0;i<4;i++){
      u32 t=base+(u32)i;
      if (t>=nc) break;
      u64 c0=ca[i], c1=cb[i]; u32 v=vv[i];
      u32 j=(u32)list[t]&0x1FFFu;
      u32 tp=t+4;
      if (tp<nc){
        u32 e2=(u32)list[tp]; u32 j2=e2&0x1FFFu; u32 wmax2=j2>>6;
        const u64* cp=cmat+(size_t)j2*CSTRIDE;
        ca[i]=((u32)lane<=wmax2)?cp[lane]:0ull;
        cb[i]=((u32)(lane+64)<=wmax2)?cp[lane+64]:0ull;
        vv[i]=(e2>>15)&1u;
      } else { ca[i]=0ull; cb[i]=0ull; vv[i]=0u; }
      bool hit = (((c0&kw0)|(c1&kw1)) != 0ull);
      bool any = __ballot(hit) != 0ull;
      if (!any && v){
        u32 w=j>>6, b=j&63u;
        if ((u32)lane==w)        kw0 |= (1ull<<b);
        if ((u32)lane==(w-64u))  kw1 |= (1ull<<b);
      }
    }
  }
  if (kw0) atomicOr(&kept[lane], kw0);
  if (lane<13 && kw1) atomicOr(&kept[64+lane], kw1);
}

// ---------------- final outputs -------------------------------------------
__global__ void k_out(const u64* __restrict__ kept, const float4* __restrict__ srawb,
                      const float* __restrict__ ssval, const u32* __restrict__ slab,
                      float* __restrict__ out)
{
  int t=blockIdx.x*blockDim.x+threadIdx.x;
  if (t<M_TOT){
    u32 kb=(u32)((kept[t>>6]>>(t&63))&1ull);
    float kf=kb?1.0f:0.0f;
    float4 b=srawb[t];
    out[4*t+0]=fminf(fmaxf(b.x/1280.0f,0.0f),1.0f)*kf;
    out[4*t+1]=fminf(fmaxf(b.y/1280.0f,0.0f),1.0f)*kf;
    out[4*t+2]=fminf(fmaxf(b.z/1280.0f,0.0f),1.0f)*kf;
    out[4*t+3]=fminf(fmaxf(b.w/1280.0f,0.0f),1.0f)*kf;
    out[19600+t]=ssval[t]*kf;
    out[24500+t]=(float)slab[t];
    out[29400+t]=kf;
  }
}

// ---------------- host ----------------------------------------------------
extern "C" void kernel_launch(void* const* d_in, const int* in_sizes, int n_in,
                              void* d_out, int out_size, void* d_ws, size_t ws_size,
                              hipStream_t stream)
{
  const float* cls[5]={nullptr,nullptr,nullptr,nullptr,nullptr};
  const float* box[5]={nullptr,nullptr,nullptr,nullptr,nullptr};
  static const int clsEl[5]={18432000,4608000,1152000,288000,72000};
  static const int boxEl[5]={921600,230400,57600,14400,3600};
  for (int i=0;i<n_in;i++){
    int sz=in_sizes[i];
    bool done=false;
    for (int l=0;l<5 && !done;l++){
      if (sz==clsEl[l] && !cls[l]){ cls[l]=(const float*)d_in[i]; done=true; }
      else if (sz==boxEl[l] && !box[l]){ box[l]=(const float*)d_in[i]; done=true; }
    }
  }
  unsigned char* ws=(unsigned char*)d_ws;
  u32* cnt   = (u32*)(ws+OFF_CNT);
  u32* flags = (u32*)(ws+OFF_FLAG);
  u64* kept  = (u64*)(ws+OFF_KEPT);
  u32* cand  = (u32*)(ws+OFF_CAND);
  u64* keyA  = (u64*)(ws+OFF_KEY);
  float4* rawbA=(float4*)(ws+OFF_RAWB);
  float4* offbA=(float4*)(ws+OFF_OFFB);
  u32* labA  = (u32*)(ws+OFF_LAB);
  float* svalA=(float*)(ws+OFF_SVAL);
  u32* validA=(u32*)(ws+OFF_VALID);
  float4* srawb=(float4*)(ws+OFF_SRAWB);
  float4* soffb=(float4*)(ws+OFF_SOFFB);
  u32* slab  = (u32*)(ws+OFF_SLAB);
  float* ssval=(float*)(ws+OFF_SSVAL);
  u32* svalid=(u32*)(ws+OFF_SVALID);
  u64* cmat  = (u64*)(ws+OFF_CMAT);
  float* out = (float*)d_out;

  hipMemsetAsync(ws, 0, ZERO_BYTES, stream);

  k_collect<<<dim3(NBLK),dim3(256),0,stream>>>(cls[0],cls[1],cls[2],cls[3],cls[4],cnt,cand,flags,0);
  k_fbmark <<<dim3(1),dim3(64),0,stream>>>(cnt,flags);
  k_collect<<<dim3(NBLK),dim3(256),0,stream>>>(cls[0],cls[1],cls[2],cls[3],cls[4],cnt,cand,flags,1);
  k_fbmark <<<dim3(1),dim3(64),0,stream>>>(cnt,flags);
  k_collect<<<dim3(NBLK),dim3(256),0,stream>>>(cls[0],cls[1],cls[2],cls[3],cls[4],cnt,cand,flags,2);

  k_select<<<dim3(5),dim3(1024),0,stream>>>(cnt,cand,
      (const float4*)box[0],(const float4*)box[1],(const float4*)box[2],
      (const float4*)box[3],(const float4*)box[4],
      keyA,rawbA,offbA,labA,svalA,validA);

  k_rank  <<<dim3(77),dim3(256),0,stream>>>(keyA,rawbA,offbA,labA,svalA,validA,
                                            srawb,soffb,slab,ssval,svalid);
  k_cmat  <<<dim3(NBLK_CMAT),dim3(256),0,stream>>>(soffb,cmat);
  k_scan  <<<dim3(80),dim3(64),0,stream>>>(cmat,svalid,slab,kept);
  k_out   <<<dim3(20),dim3(256),0,stream>>>(kept,srawb,ssval,slab,out);
}

// Round 6
// 290.932 us; speedup vs baseline: 1.4558x; 1.1712x over previous
//
#include <hip/hip_runtime.h>
#include <cmath>

typedef unsigned int u32;
typedef unsigned long long u64;

#define NLEV 5
#define M_TOT 4900
#define NWORDS 77          // ceil(4900/64)
#define CSTRIDE 80         // cmat row stride in u64 words (640B)
#define CAP 65536          // candidate capacity per level
#define PAD_M 4928
#define NBLK 1501          // collect blocks (per-level partitioned, 64 floats/thread)
#define LDSQ 1024          // per-block LDS candidate queue
#define TIE_CAP 2048
#define NBLK_CMAT 3003     // 77*78/2 triangular tiles
#define HBINS 4096         // 12-bit histogram in k_select LDS
#define UCAP 128           // max undecided nodes on the fast path

__constant__ int   c_KLVL[5] = {1000,1000,1000,1000,900};
__constant__ int   c_LOFF[5] = {0,1000,2000,3000,4000};
__constant__ int   c_N4[5]   = {4608000,1152000,288000,72000,18000}; // float4s per level
__constant__ int   c_BB[6]   = {0,1125,1407,1478,1496,1501};         // block ranges per level
__constant__ float c_THR[5]  = {1.0f,0.65f,0.30f,-0.15f,-0.60f};

// ---- workspace layout (bytes) ----
constexpr size_t OFF_CNT   = 0;       // u32[8]
constexpr size_t OFF_KEPT  = 256;     // u64[96]
constexpr size_t OFF_HPRED = 1024;    // u64[96]
constexpr size_t ZERO_BYTES= 4096;
constexpr size_t OFF_CAND  = ZERO_BYTES;                             // u32[5*CAP*2]
constexpr size_t OFF_KEY   = OFF_CAND + (size_t)NLEV*CAP*8;          // u64[PAD_M]
constexpr size_t OFF_RAWB  = OFF_KEY   + (size_t)PAD_M*8;            // float4
constexpr size_t OFF_OFFB  = OFF_RAWB  + (size_t)PAD_M*16;
constexpr size_t OFF_LAB   = OFF_OFFB  + (size_t)PAD_M*16;           // u32
constexpr size_t OFF_SVAL  = OFF_LAB   + (size_t)PAD_M*4;            // f32
constexpr size_t OFF_VALID = OFF_SVAL  + (size_t)PAD_M*4;            // u32
constexpr size_t OFF_SRAWB = OFF_VALID + (size_t)PAD_M*4;            // float4
constexpr size_t OFF_SOFFB = OFF_SRAWB + (size_t)PAD_M*16;
constexpr size_t OFF_SLAB  = OFF_SOFFB + (size_t)PAD_M*16;           // u32
constexpr size_t OFF_SSVAL = OFF_SLAB  + (size_t)PAD_M*4;            // f32
constexpr size_t OFF_SVALID= OFF_SSVAL + (size_t)PAD_M*4;            // u32
constexpr size_t OFF_CMAT  = (OFF_SVALID + (size_t)PAD_M*4 + 255) & ~(size_t)255;

__device__ __forceinline__ u32 okey(u32 u){
  return (u & 0x80000000u) ? ~u : (u | 0x80000000u);
}

__device__ __forceinline__ u32 lane_prior(u64 mask){
  return __builtin_amdgcn_mbcnt_hi((u32)(mask>>32),
         __builtin_amdgcn_mbcnt_lo((u32)mask, 0u));
}

// wave-aggregated LDS counter allocation; wave-uniform execution required.
__device__ __forceinline__ u32 wave_alloc(u32* ctr, bool take){
  u64 mask = __ballot(take);
  if (mask==0ull) return 0xFFFFFFFFu;
  u32 prior = lane_prior(mask);
  u32 total = (u32)__popcll(mask);
  int leader = __ffsll((unsigned long long)mask) - 1;
  u32 base = 0;
  if (take && prior==0u) base = atomicAdd(ctr, total);
  base = __shfl(base, leader, 64);
  return take ? (base + prior) : 0xFFFFFFFFu;
}

// ---------------- candidate collection (pure streaming pass) --------------
__global__ void __launch_bounds__(256)
k_collect(const float* __restrict__ a0, const float* __restrict__ a1,
          const float* __restrict__ a2, const float* __restrict__ a3,
          const float* __restrict__ a4,
          u32* __restrict__ cnt, u32* __restrict__ cand)
{
  const int b = blockIdx.x;
  const int l = (b<c_BB[1])?0:(b<c_BB[2])?1:(b<c_BB[3])?2:(b<c_BB[4])?3:4;
  const float* __restrict__ p = (l==0)?a0:(l==1)?a1:(l==2)?a2:(l==3)?a3:a4;
  const float T = c_THR[l];
  const int n4l = c_N4[l];
  const int lb  = b - c_BB[l];
  const int base4 = lb*4096 + (int)threadIdx.x;

  __shared__ u32 lcnt, gbase;
  __shared__ u32 lbitsA[LDSQ];
  __shared__ u32 lidxA[LDSQ];
  if (threadIdx.x==0) lcnt=0u;
  __syncthreads();

  float4 xs[16];
#pragma unroll
  for (int u=0;u<16;u++){
    int q = base4 + u*256;
    int qc = (q < n4l) ? q : (n4l-1);
    xs[u] = *(const float4*)(p + (size_t)qc*4u);
  }
  u32* cdL = cand + (size_t)l*CAP*2u;
#pragma unroll
  for (int u=0;u<16;u++){
    int q = base4 + u*256;
    if (q < n4l){
      float v[4]={xs[u].x,xs[u].y,xs[u].z,xs[u].w};
#pragma unroll
      for (int i=0;i<4;i++){
        if (v[i] > T){
          u32 s = atomicAdd(&lcnt,1u);
          u32 bits = __float_as_uint(v[i]);
          u32 idx  = (u32)(q*4+i);
          if (s < LDSQ){ lbitsA[s]=bits; lidxA[s]=idx; }
          else {
            u32 pp = atomicAdd(&cnt[l],1u);            // rare spill, exact count
            if (pp < CAP){ u32* d=cdL+(size_t)pp*2u; d[0]=bits; d[1]=idx; }
          }
        }
      }
    }
  }
  __syncthreads();
  if (threadIdx.x==0){
    u32 m = min(lcnt,(u32)LDSQ);
    gbase = (m>0u) ? atomicAdd(&cnt[l],m) : 0xFFFFFFFFu;
  }
  __syncthreads();
  u32 m = min(lcnt,(u32)LDSQ);
  for (u32 i=threadIdx.x;i<m;i+=256u){
    u32 pp = gbase + i;
    if (pp < CAP){ u32* d=cdL+(size_t)pp*2u; d[0]=lbitsA[i]; d[1]=lidxA[i]; }
  }
}

// ---------------- record emit helpers --------------------------------------
__device__ __forceinline__ void emit_record(int l, int slot, u32 lbits, u32 idx,
    const float4* __restrict__ boxp, u64* keyA, float4* rawbA, float4* offbA,
    u32* labA, float* svalA, u32* validA)
{
#pragma clang fp contract(off)
  float x = __uint_as_float(lbits);
  float s = (float)(1.0 / (1.0 + exp(-(double)x)));
  u32 valid = (s > 0.05f) ? 1u : 0u;
  u32 label = idx % 80u;
  u32 anchor = idx / 80u;
  float4 bx = boxp[anchor];
  float off = (float)label * 1281.0f;   // label * (IMG + 1)
  float4 ob;
  ob.x = bx.x + off; ob.y = bx.y + off; ob.z = bx.z + off; ob.w = bx.w + off;
  u32 pos = ((u32)l << 25) | idx;
  u32 khi = valid ? okey(lbits) : 0u;
  int g = c_LOFF[l] + slot;
  keyA[g]  = ((u64)khi << 32) | (u64)(u32)(~pos);
  rawbA[g] = bx; offbA[g] = ob; labA[g] = label;
  svalA[g] = valid ? s : 0.0f; validA[g] = valid;
}

__device__ __forceinline__ void emit_dummy(int l, int slot,
    u64* keyA, float4* rawbA, float4* offbA, u32* labA, float* svalA, u32* validA)
{
  u32 pos = ((u32)l<<25) | (0x1FFFFFFu - (u32)slot);  // unique, beyond real idx
  int g = c_LOFF[l]+slot;
  float4 z; z.x=z.y=z.z=z.w=0.0f;
  keyA[g]=(u64)(u32)(~pos);
  rawbA[g]=z; offbA[g]=z; labA[g]=0u; svalA[g]=0.0f; validA[g]=0u;
}

// --- per-level exact top-k via 12-bit LDS histogram cutoff + tie refine ----
// Includes a data-dependent in-kernel fallback rescan (never triggers for the
// bench distribution; preserves exactness for any input).
__global__ void __launch_bounds__(1024)
k_select(u32* __restrict__ cnt, u32* __restrict__ cand,
         const float* __restrict__ a0, const float* __restrict__ a1,
         const float* __restrict__ a2, const float* __restrict__ a3,
         const float* __restrict__ a4,
         const float4* b0, const float4* b1, const float4* b2,
         const float4* b3, const float4* b4,
         u64* keyA, float4* rawbA, float4* offbA,
         u32* labA, float* svalA, u32* validA)
{
  const int l = blockIdx.x;
  const float4* boxp = (l==0)?b0:(l==1)?b1:(l==2)?b2:(l==3)?b3:b4;
  const float* __restrict__ p = (l==0)?a0:(l==1)?a1:(l==2)?a2:(l==3)?a3:a4;
  u32* cdL = cand + (size_t)l*CAP*2u;
  const u32* cd = cdL;
  const int k = c_KLVL[l];
  u32 count = min(cnt[l], (u32)CAP);

  __shared__ u32 lhist[4][HBINS];      // 4 replicas to cut same-address chains
  __shared__ u32 sufw[16];
  __shared__ u32 c0_s, kk_s, cnt_s;
  __shared__ u32 emit_s, ntie_s;
  __shared__ u32 tb[TIE_CAP], ti[TIE_CAP];

  const u32 tid = threadIdx.x;
  const u32 lane = tid & 63u;
  const u32 wave = tid >> 6;
  if (tid==0){ emit_s=0u; ntie_s=0u; c0_s=0u; kk_s=0u; }
  for (u32 i=tid;i<4u*HBINS;i+=1024u) ((u32*)lhist)[i]=0u;
  __syncthreads();

  // ---- fallback rescan (correctness-only path, never runs for bench data) --
  if (count < (u32)k){
    const int nElem = c_N4[l]*4;
    float Tprev = c_THR[l];
    for (int r=1; r<=7 && count<(u32)k; r++){
      float Tn = (r<7) ? (c_THR[l] - 1.5f*(float)r) : -3.0e38f;
      for (u32 i=tid; i<(u32)nElem; i+=1024u){
        float x = p[i];
        if (x>Tn && x<=Tprev){
          u32 pp = atomicAdd(&cnt[l],1u);
          if (pp<CAP){ u32* d=cdL+(size_t)pp*2u; d[0]=__float_as_uint(x); d[1]=i; }
        }
      }
      __syncthreads();
      if (tid==0) cnt_s = atomicAdd(&cnt[l],0u);
      __syncthreads();
      count = min(cnt_s,(u32)CAP);
      Tprev = Tn;
    }
  }

  if (count > (u32)k){
    // --- pass A: 12-bit histogram of okey ---
    const u32 rep = wave & 3u;
    for (u32 i=tid;i<count;i+=1024u)
      atomicAdd(&lhist[rep][okey(cd[2*(size_t)i])>>20], 1u);
    __syncthreads();
    // merge replicas: thread owns bins [tid*4, tid*4+4)
    u32 base = tid*4u;
    u32 hb[4]; u32 ls=0u;
#pragma unroll
    for (int b2_=0;b2_<4;b2_++){
      u32 h = lhist[0][base+(u32)b2_]+lhist[1][base+(u32)b2_]
            + lhist[2][base+(u32)b2_]+lhist[3][base+(u32)b2_];
      hb[b2_]=h; ls+=h;
    }
    // suffix-scan across threads (descending bin index)
    u32 x = ls;
#pragma unroll
    for (int off=1; off<64; off<<=1){
      u32 y = __shfl_down(x, off, 64);
      if (lane + (u32)off < 64u) x += y;
    }
    if (lane==0u) sufw[wave]=x;
    __syncthreads();
    u32 wsuf=0u;
    for (u32 w=wave+1u;w<16u;w++) wsuf += sufw[w];
    u32 suffix_after = wsuf + (x - ls);  // strictly above my 4-bin chunk
    if (suffix_after < (u32)k && (u32)k <= suffix_after + ls){
      u32 run = suffix_after;
      for (int b2_=3;b2_>=0;b2_--){
        u32 h = hb[b2_];
        run += h;
        if (run >= (u32)k){ c0_s = base+(u32)b2_; kk_s = (u32)k - (run - h); break; }
      }
    }
    __syncthreads();
    const u32 c0 = c0_s, kk = kk_s;

    // --- pass B: emit definite winners, stash tie-bin ---
    u32 iters = (count + 1023u)/1024u;
    for (u32 it=0; it<iters; it++){
      u32 i = it*1024u + tid;
      bool in = i < count;
      u32 bits = in ? cd[2*(size_t)i] : 0u;
      u32 idx  = in ? cd[2*(size_t)i+1] : 0u;
      u32 h    = okey(bits)>>20;
      bool hi  = in && (h > c0);
      bool tie = in && (h == c0);
      u32 s = wave_alloc(&emit_s, hi);
      if (hi && s < (u32)k)
        emit_record(l,(int)s,bits,idx,boxp,keyA,rawbA,offbA,labA,svalA,validA);
      u32 t = wave_alloc(&ntie_s, tie);
      if (tie && t < (u32)TIE_CAP){ tb[t]=bits; ti[t]=idx; }
    }
    __syncthreads();

    // --- exact refine within tie bin (full key desc, idx asc) ---
    u32 nt = min(ntie_s,(u32)TIE_CAP);
    for (u32 e=tid;e<nt;e+=1024u){
      u32 mk = okey(tb[e]); u32 mi = ti[e];
      u32 r=0u;
      for (u32 e2=0;e2<nt;e2++){
        u32 k2 = okey(tb[e2]);
        r += (k2>mk || (k2==mk && ti[e2]<mi)) ? 1u : 0u;
      }
      if (r < kk){
        u32 s = atomicAdd(&emit_s,1u);
        if (s < (u32)k)
          emit_record(l,(int)s,tb[e],mi,boxp,keyA,rawbA,offbA,labA,svalA,validA);
      }
    }
  } else {
    u32 iters = (count + 1023u)/1024u;
    for (u32 it=0; it<iters; it++){
      u32 i = it*1024u + tid;
      bool in = i < count;
      u32 bits = in ? cd[2*(size_t)i] : 0u;
      u32 idx  = in ? cd[2*(size_t)i+1] : 0u;
      u32 s = wave_alloc(&emit_s, in);
      if (in && s < (u32)k)
        emit_record(l,(int)s,bits,idx,boxp,keyA,rawbA,offbA,labA,svalA,validA);
    }
  }
  __syncthreads();
  u32 em = min(emit_s,(u32)k);
  for (u32 i=em+tid;i<(u32)k;i+=1024u)
    emit_dummy(l,(int)i,keyA,rawbA,offbA,labA,svalA,validA);
}

// ------- global sort via rank-by-counting (unique keys) + fused gather -----
__global__ void __launch_bounds__(256)
k_rank(const u64* __restrict__ keyA,
       const float4* __restrict__ rawbA, const float4* __restrict__ offbA,
       const u32* __restrict__ labA, const float* __restrict__ svalA,
       const u32* __restrict__ validA,
       float4* srawb, float4* soffb, u32* slab, float* ssval, u32* svalid)
{
  __shared__ u64 sk[M_TOT];
  __shared__ u32 part[3][64];
  for (int i=threadIdx.x;i<M_TOT;i+=256) sk[i]=keyA[i];
  __syncthreads();
  int lane = threadIdx.x & 63;
  int wave = threadIdx.x >> 6;
  int i = blockIdx.x*64 + lane;
  u64 mk = sk[(i<M_TOT)?i:0];
  int j0 = wave*1225;
  u32 r=0;
#pragma unroll 5
  for (int j=j0;j<j0+1225;j++) r += (sk[j]>mk)?1u:0u;
  if (wave) part[wave-1][lane]=r;
  __syncthreads();
  if (wave==0 && i<M_TOT){
    r += part[0][lane]+part[1][lane]+part[2][lane];
    srawb[r]=rawbA[i]; soffb[r]=offbA[i]; slab[r]=labA[i];
    ssval[r]=svalA[i]; svalid[r]=validA[i];
  }
}

// ------- predecessor bitmask matrix: triangular 64x64 tiles + haspred ------
__global__ void __launch_bounds__(256)
k_cmat(const float4* __restrict__ soffb, u64* __restrict__ cmat,
       u64* __restrict__ haspred)
{
#pragma clang fp contract(off)
  int bi = blockIdx.x;
  int jt = (int)((sqrtf(8.0f*(float)bi+1.0f)-1.0f)*0.5f);
  while ((jt+1)*(jt+2)/2 <= bi) jt++;
  while (jt*(jt+1)/2 > bi) jt--;
  int wt = bi - jt*(jt+1)/2;

  __shared__ float rx[64],ry[64],rz[64],rw[64],ra[64];
  __shared__ float cx[64],cy[64],cz[64],cw[64],cae[64];
  int tid = threadIdx.x;
  if (tid<64){
    float4 b = soffb[wt*64+tid];
    rx[tid]=b.x; ry[tid]=b.y; rz[tid]=b.z; rw[tid]=b.w;
    ra[tid]=fmaxf(b.z-b.x,0.0f)*fmaxf(b.w-b.y,0.0f);
  } else if (tid<128){
    int c=tid-64;
    float4 b = soffb[jt*64+c];
    cx[c]=b.x; cy[c]=b.y; cz[c]=b.z; cw[c]=b.w;
    cae[c]=fmaxf(b.z-b.x,0.0f)*fmaxf(b.w-b.y,0.0f);
  }
  __syncthreads();
  int lane = tid & 63;
  int wave = tid >> 6;
  int rowg = wt*64 + lane;
  float bx=rx[lane], by=ry[lane], bz=rz[lane], bw=rw[lane], bar=ra[lane];
  for (int cc=wave*16; cc<wave*16+16; cc++){
    int jg = jt*64 + cc;
    if (jg >= M_TOT) continue;          // uniform across wave
    float jx=cx[cc], jy=cy[cc], jz=cz[cc], jw=cw[cc], jar=cae[cc];
    float ltx=fmaxf(bx,jx), lty=fmaxf(by,jy);
    float rbx=fminf(bz,jz), rby=fminf(bw,jw);
    float wx=fmaxf(rbx-ltx,0.0f), wy=fmaxf(rby-lty,0.0f);
    float inter=wx*wy;
    float iou = inter/(bar+jar-inter+1e-9f);
    bool bit = (rowg < jg) && (iou > 0.6f);
    u64 word = __ballot(bit);
    if (lane==0){
      cmat[(size_t)jg*CSTRIDE + (size_t)wt] = word;
      if (word) atomicOr(&haspred[jg>>6], 1ull<<(jg&63));
    }
  }
}

// ------- greedy resolution: only nodes WITH predecessors are sequential ----
__global__ void __launch_bounds__(256)
k_resolve(const u64* __restrict__ cmat, const u32* __restrict__ svalid,
          const u64* __restrict__ haspred, u64* __restrict__ kept)
{
  __shared__ u64 k0[NWORDS];            // decided-kept words (later += undec kept)
  __shared__ u64 uw[NWORDS];            // undecided (valid & haspred) words
  __shared__ u32 ubase[NWORDS];         // rank base per word
  __shared__ unsigned short ulist[UCAP];
  __shared__ u64 pmask[UCAP][2];        // compact undec-pred masks
  __shared__ u32 dhit[UCAP];
  __shared__ u32 nu_s;
  const u32 tid=threadIdx.x, lane=tid&63u, wave=tid>>6;

  for (u32 w=wave; w<NWORDS; w+=4){
    int j = (int)(w*64u+lane);
    u32 sv = (j<M_TOT)? svalid[j] : 0u;
    u64 hp = haspred[w];
    bool hpb = (hp>>lane)&1ull;
    u64 keepb = __ballot(sv && !hpb);
    u64 undb  = __ballot(sv && hpb);
    if (lane==0){ k0[w]=keepb; uw[w]=undb; }
  }
  __syncthreads();
  if (tid==0){
    u32 n=0;
    for (int w=0;w<NWORDS;w++){
      ubase[w]=n;
      u64 U=uw[w];
      while(U){ int b=__builtin_ctzll(U); U&=U-1ull;
                if (n<UCAP) ulist[n]=(unsigned short)(w*64+b); n++; }
    }
    nu_s=n;
  }
  __syncthreads();
  u32 nu = nu_s;

  if (nu>0u && nu<=UCAP){
    // parallel: per undec node, hit-vs-decided and compact pred mask
    for (u32 t=tid; t<nu; t+=256u){
      u32 j = (u32)ulist[t];
      const u64* row = cmat + (size_t)j*CSTRIDE;
      u32 wmax = j>>6;
      u64 hit=0ull, pm0=0ull, pm1=0ull;
      for (u32 w=0; w<=wmax; w++){
        u64 rw = row[w];
        hit |= rw & k0[w];
        u64 ub = rw & uw[w];
        while(ub){
          int b=__builtin_ctzll(ub); ub&=ub-1ull;
          u32 idx = ubase[w] + (u32)__popcll(uw[w] & ((b==0)?0ull:((1ull<<b)-1ull)));
          if (idx<64u) pm0 |= 1ull<<idx; else pm1 |= 1ull<<(idx-64u);
        }
      }
      dhit[t] = (hit!=0ull)?1u:0u;
      pmask[t][0]=pm0; pmask[t][1]=pm1;
    }
    __syncthreads();
    if (tid==0){
      u64 ku0=0ull, ku1=0ull;
      for (u32 t=0;t<nu;t++){
        bool sup = dhit[t] || ((pmask[t][0]&ku0)|(pmask[t][1]&ku1))!=0ull;
        if (!sup){
          if (t<64u) ku0|=1ull<<t; else ku1|=1ull<<(t-64u);
          u32 j=(u32)ulist[t];
          k0[j>>6] |= 1ull<<(j&63u);
        }
      }
    }
    __syncthreads();
  } else if (nu>UCAP){
    // exact slow path (never triggers for bench data)
    if (tid==0){
      for (int w=0;w<NWORDS;w++){
        u64 U=uw[w];
        while(U){
          int b=__builtin_ctzll(U); U&=U-1ull;
          u32 j=(u32)(w*64+b);
          const u64* row = cmat + (size_t)j*CSTRIDE;
          u64 hit=0ull; u32 wmax=j>>6;
          for (u32 w2=0;w2<=wmax;w2++) hit |= row[w2] & k0[w2];
          if (hit==0ull) k0[j>>6] |= 1ull<<(j&63u);
        }
      }
    }
    __syncthreads();
  }
  for (u32 w=tid; w<NWORDS; w+=256u) kept[w]=k0[w];
}

// ---------------- final outputs -------------------------------------------
__global__ void k_out(const u64* __restrict__ kept, const float4* __restrict__ srawb,
                      const float* __restrict__ ssval, const u32* __restrict__ slab,
                      float* __restrict__ out)
{
  int t=blockIdx.x*blockDim.x+threadIdx.x;
  if (t<M_TOT){
    u32 kb=(u32)((kept[t>>6]>>(t&63))&1ull);
    float kf=kb?1.0f:0.0f;
    float4 b=srawb[t];
    out[4*t+0]=fminf(fmaxf(b.x/1280.0f,0.0f),1.0f)*kf;
    out[4*t+1]=fminf(fmaxf(b.y/1280.0f,0.0f),1.0f)*kf;
    out[4*t+2]=fminf(fmaxf(b.z/1280.0f,0.0f),1.0f)*kf;
    out[4*t+3]=fminf(fmaxf(b.w/1280.0f,0.0f),1.0f)*kf;
    out[19600+t]=ssval[t]*kf;
    out[24500+t]=(float)slab[t];
    out[29400+t]=kf;
  }
}

// ---------------- host ----------------------------------------------------
extern "C" void kernel_launch(void* const* d_in, const int* in_sizes, int n_in,
                              void* d_out, int out_size, void* d_ws, size_t ws_size,
                              hipStream_t stream)
{
  const float* cls[5]={nullptr,nullptr,nullptr,nullptr,nullptr};
  const float* box[5]={nullptr,nullptr,nullptr,nullptr,nullptr};
  static const int clsEl[5]={18432000,4608000,1152000,288000,72000};
  static const int boxEl[5]={921600,230400,57600,14400,3600};
  for (int i=0;i<n_in;i++){
    int sz=in_sizes[i];
    bool done=false;
    for (int l=0;l<5 && !done;l++){
      if (sz==clsEl[l] && !cls[l]){ cls[l]=(const float*)d_in[i]; done=true; }
      else if (sz==boxEl[l] && !box[l]){ box[l]=(const float*)d_in[i]; done=true; }
    }
  }
  unsigned char* ws=(unsigned char*)d_ws;
  u32* cnt   = (u32*)(ws+OFF_CNT);
  u64* kept  = (u64*)(ws+OFF_KEPT);
  u64* hpred = (u64*)(ws+OFF_HPRED);
  u32* cand  = (u32*)(ws+OFF_CAND);
  u64* keyA  = (u64*)(ws+OFF_KEY);
  float4* rawbA=(float4*)(ws+OFF_RAWB);
  float4* offbA=(float4*)(ws+OFF_OFFB);
  u32* labA  = (u32*)(ws+OFF_LAB);
  float* svalA=(float*)(ws+OFF_SVAL);
  u32* validA=(u32*)(ws+OFF_VALID);
  float4* srawb=(float4*)(ws+OFF_SRAWB);
  float4* soffb=(float4*)(ws+OFF_SOFFB);
  u32* slab  = (u32*)(ws+OFF_SLAB);
  float* ssval=(float*)(ws+OFF_SSVAL);
  u32* svalid=(u32*)(ws+OFF_SVALID);
  u64* cmat  = (u64*)(ws+OFF_CMAT);
  float* out = (float*)d_out;

  hipMemsetAsync(ws, 0, ZERO_BYTES, stream);

  k_collect<<<dim3(NBLK),dim3(256),0,stream>>>(cls[0],cls[1],cls[2],cls[3],cls[4],cnt,cand);

  k_select<<<dim3(5),dim3(1024),0,stream>>>(cnt,cand,
      cls[0],cls[1],cls[2],cls[3],cls[4],
      (const float4*)box[0],(const float4*)box[1],(const float4*)box[2],
      (const float4*)box[3],(const float4*)box[4],
      keyA,rawbA,offbA,labA,svalA,validA);

  k_rank  <<<dim3(77),dim3(256),0,stream>>>(keyA,rawbA,offbA,labA,svalA,validA,
                                            srawb,soffb,slab,ssval,svalid);
  k_cmat  <<<dim3(NBLK_CMAT),dim3(256),0,stream>>>(soffb,cmat,hpred);
  k_resolve<<<dim3(1),dim3(256),0,stream>>>(cmat,svalid,hpred,kept);
  k_out   <<<dim3(20),dim3(256),0,stream>>>(kept,srawb,ssval,slab,out);
}

// Round 7
// 285.431 us; speedup vs baseline: 1.4839x; 1.0193x over previous
//
#include <hip/hip_runtime.h>
#include <cmath>

typedef unsigned int u32;
typedef unsigned long long u64;

#define NLEV 5
#define M_TOT 4900
#define NWORDS 77          // ceil(4900/64)
#define CSTRIDE 80         // cmat row stride in u64 words (640B)
#define PAD_M 4928
#define NBLK 1501          // collect blocks (per-level partitioned, 64 floats/thread)
#define LDSQ 2048          // per-block LDS candidate queue (level-4 max ~1200)
#define NSH 32             // flush-counter shards per level
#define SHCAP 2048         // entries per shard region
#define OVCAP 16384        // per-level overflow region entries
#define LVST (NSH*SHCAP + OVCAP)   // entries per level region = 81920
#define TIE_CAP 2048
#define NBLK_CMAT 3003     // 77*78/2 triangular tiles
#define HBINS 4096         // linear-quantized histogram bins
#define UCAP 128           // max undecided nodes on the NMS fast path

__constant__ int   c_KLVL[5] = {1000,1000,1000,1000,900};
__constant__ int   c_LOFF[5] = {0,1000,2000,3000,4000};
__constant__ int   c_N4[5]   = {4608000,1152000,288000,72000,18000}; // float4s per level
__constant__ int   c_BB[6]   = {0,1125,1407,1478,1496,1501};         // block ranges per level
__constant__ float c_THR[5]  = {1.0f,0.65f,0.30f,-0.15f,-0.60f};

// ---- workspace layout (bytes) ----
constexpr size_t OFF_CNT   = 0;       // u32[5*NSH]
constexpr size_t OFF_OCNT  = 768;     // u32[8]
constexpr size_t OFF_KEPT  = 1024;    // u64[96]
constexpr size_t OFF_HPRED = 2048;    // u64[96]
constexpr size_t ZERO_BYTES= 4096;
constexpr size_t OFF_CAND  = 4096;                                   // u32[5*LVST*2]
constexpr size_t OFF_KEY   = OFF_CAND + (size_t)NLEV*LVST*8;         // u64[PAD_M]
constexpr size_t OFF_RAWB  = OFF_KEY   + (size_t)PAD_M*8;            // float4
constexpr size_t OFF_OFFB  = OFF_RAWB  + (size_t)PAD_M*16;
constexpr size_t OFF_LAB   = OFF_OFFB  + (size_t)PAD_M*16;           // u32
constexpr size_t OFF_SVAL  = OFF_LAB   + (size_t)PAD_M*4;            // f32
constexpr size_t OFF_VALID = OFF_SVAL  + (size_t)PAD_M*4;            // u32
constexpr size_t OFF_SRAWB = OFF_VALID + (size_t)PAD_M*4;            // float4
constexpr size_t OFF_SOFFB = OFF_SRAWB + (size_t)PAD_M*16;
constexpr size_t OFF_SLAB  = OFF_SOFFB + (size_t)PAD_M*16;           // u32
constexpr size_t OFF_SSVAL = OFF_SLAB  + (size_t)PAD_M*4;            // f32
constexpr size_t OFF_SVALID= OFF_SSVAL + (size_t)PAD_M*4;            // u32
constexpr size_t OFF_CMAT  = (OFF_SVALID + (size_t)PAD_M*4 + 255) & ~(size_t)255;

__device__ __forceinline__ u32 okey(u32 u){
  return (u & 0x80000000u) ? ~u : (u | 0x80000000u);
}

__device__ __forceinline__ u32 qbin(u32 bits, float T){
  float x = __uint_as_float(bits);
  int b = (int)((x - T)*800.0f);
  return (u32)max(0, min(HBINS-1, b));
}

__device__ __forceinline__ u32 lane_prior(u64 mask){
  return __builtin_amdgcn_mbcnt_hi((u32)(mask>>32),
         __builtin_amdgcn_mbcnt_lo((u32)mask, 0u));
}

// wave-aggregated LDS counter allocation; wave-uniform execution required.
__device__ __forceinline__ u32 wave_alloc(u32* ctr, bool take){
  u64 mask = __ballot(take);
  if (mask==0ull) return 0xFFFFFFFFu;
  u32 prior = lane_prior(mask);
  u32 total = (u32)__popcll(mask);
  int leader = __ffsll((unsigned long long)mask) - 1;
  u32 base = 0;
  if (take && prior==0u) base = atomicAdd(ctr, total);
  base = __shfl(base, leader, 64);
  return take ? (base + prior) : 0xFFFFFFFFu;
}

// ---------------- candidate collection (pure streaming pass) --------------
// Flush counters sharded 32-way per level: same-address atomic chain <= ~35.
__global__ void __launch_bounds__(256)
k_collect(const float* __restrict__ a0, const float* __restrict__ a1,
          const float* __restrict__ a2, const float* __restrict__ a3,
          const float* __restrict__ a4,
          u32* __restrict__ cnt, u32* __restrict__ ocnt, u32* __restrict__ cand)
{
  const int b = blockIdx.x;
  const int l = (b<c_BB[1])?0:(b<c_BB[2])?1:(b<c_BB[3])?2:(b<c_BB[4])?3:4;
  const float* __restrict__ p = (l==0)?a0:(l==1)?a1:(l==2)?a2:(l==3)?a3:a4;
  const float T = c_THR[l];
  const int n4l = c_N4[l];
  const int lb  = b - c_BB[l];
  const int shard = lb & (NSH-1);
  const int base4 = lb*4096 + (int)threadIdx.x;

  __shared__ u32 lcnt, gbase;
  __shared__ u32 lbitsA[LDSQ];
  __shared__ u32 lidxA[LDSQ];
  if (threadIdx.x==0) lcnt=0u;
  __syncthreads();

  float4 xs[16];
#pragma unroll
  for (int u=0;u<16;u++){
    int q = base4 + u*256;
    int qc = (q < n4l) ? q : (n4l-1);
    xs[u] = *(const float4*)(p + (size_t)qc*4u);
  }
  u32* cdS = cand + ((size_t)l*LVST + (size_t)shard*SHCAP)*2u;
  u32* cdO = cand + ((size_t)l*LVST + (size_t)NSH*SHCAP)*2u;
#pragma unroll
  for (int u=0;u<16;u++){
    int q = base4 + u*256;
    if (q < n4l){
      float v[4]={xs[u].x,xs[u].y,xs[u].z,xs[u].w};
#pragma unroll
      for (int i=0;i<4;i++){
        if (v[i] > T){
          u32 s = atomicAdd(&lcnt,1u);
          u32 bits = __float_as_uint(v[i]);
          u32 idx  = (u32)(q*4+i);
          if (s < LDSQ){ lbitsA[s]=bits; lidxA[s]=idx; }
          else {
            u32 pp = atomicAdd(&ocnt[l],1u);           // rare overflow spill
            if (pp < OVCAP){ u32* d=cdO+(size_t)pp*2u; d[0]=bits; d[1]=idx; }
          }
        }
      }
    }
  }
  __syncthreads();
  if (threadIdx.x==0){
    u32 m = min(lcnt,(u32)LDSQ);
    gbase = (m>0u) ? atomicAdd(&cnt[l*NSH+shard],m) : 0xFFFFFFFFu;
  }
  __syncthreads();
  u32 m = min(lcnt,(u32)LDSQ);
  for (u32 i=threadIdx.x;i<m;i+=256u){
    u32 pp = gbase + i;
    if (pp < SHCAP){ u32* d=cdS+(size_t)pp*2u; d[0]=lbitsA[i]; d[1]=lidxA[i]; }
    else {
      u32 q = atomicAdd(&ocnt[l],1u);                  // shard-full spill (rare)
      if (q < OVCAP){ u32* d=cdO+(size_t)q*2u; d[0]=lbitsA[i]; d[1]=lidxA[i]; }
    }
  }
}

// ---------------- record emit helpers --------------------------------------
__device__ __forceinline__ void emit_record(int l, int slot, u32 lbits, u32 idx,
    const float4* __restrict__ boxp, u64* keyA, float4* rawbA, float4* offbA,
    u32* labA, float* svalA, u32* validA)
{
#pragma clang fp contract(off)
  float x = __uint_as_float(lbits);
  float s = (float)(1.0 / (1.0 + exp(-(double)x)));
  u32 valid = (s > 0.05f) ? 1u : 0u;
  u32 label = idx % 80u;
  u32 anchor = idx / 80u;
  float4 bx = boxp[anchor];
  float off = (float)label * 1281.0f;   // label * (IMG + 1)
  float4 ob;
  ob.x = bx.x + off; ob.y = bx.y + off; ob.z = bx.z + off; ob.w = bx.w + off;
  u32 pos = ((u32)l << 25) | idx;
  u32 khi = valid ? okey(lbits) : 0u;
  int g = c_LOFF[l] + slot;
  keyA[g]  = ((u64)khi << 32) | (u64)(u32)(~pos);
  rawbA[g] = bx; offbA[g] = ob; labA[g] = label;
  svalA[g] = valid ? s : 0.0f; validA[g] = valid;
}

__device__ __forceinline__ void emit_dummy(int l, int slot,
    u64* keyA, float4* rawbA, float4* offbA, u32* labA, float* svalA, u32* validA)
{
  u32 pos = ((u32)l<<25) | (0x1FFFFFFu - (u32)slot);  // unique, beyond real idx
  int g = c_LOFF[l]+slot;
  float4 z; z.x=z.y=z.z=z.w=0.0f;
  keyA[g]=(u64)(u32)(~pos);
  rawbA[g]=z; offbA[g]=z; labA[g]=0u; svalA[g]=0.0f; validA[g]=0u;
}

// --- per-level exact top-k: linear-quantized histogram cutoff + tie refine -
__global__ void __launch_bounds__(1024)
k_select(u32* __restrict__ cnt, u32* __restrict__ ocnt, u32* __restrict__ cand,
         const float* __restrict__ a0, const float* __restrict__ a1,
         const float* __restrict__ a2, const float* __restrict__ a3,
         const float* __restrict__ a4,
         const float4* b0, const float4* b1, const float4* b2,
         const float4* b3, const float4* b4,
         u64* keyA, float4* rawbA, float4* offbA,
         u32* labA, float* svalA, u32* validA)
{
  const int l = blockIdx.x;
  const float4* boxp = (l==0)?b0:(l==1)?b1:(l==2)?b2:(l==3)?b3:b4;
  const float* __restrict__ p = (l==0)?a0:(l==1)?a1:(l==2)?a2:(l==3)?a3:a4;
  const float Tl = c_THR[l];
  u32* lvbase = cand + (size_t)l*LVST*2u;
  u32* cdO = lvbase + (size_t)NSH*SHCAP*2u;
  const int k = c_KLVL[l];

  __shared__ u32 lhist[4][HBINS];      // 4 replicas
  __shared__ u32 sufw[16];
  __shared__ u32 rlen[NSH+1];
  __shared__ u32 count_s;
  __shared__ u32 c0_s, kk_s;
  __shared__ u32 emit_s, ntie_s;
  __shared__ u32 tb[TIE_CAP], ti[TIE_CAP];

  const u32 tid = threadIdx.x;
  const u32 lane = tid & 63u;
  const u32 wave = tid >> 6;
  if (tid==0){ emit_s=0u; ntie_s=0u; c0_s=0u; kk_s=0u; }
  if (tid<NSH) rlen[tid]=min(cnt[l*NSH+tid],(u32)SHCAP);
  if (tid==NSH) rlen[NSH]=min(ocnt[l],(u32)OVCAP);
  for (u32 i=tid;i<4u*HBINS;i+=1024u) ((u32*)lhist)[i]=0u;
  __syncthreads();
  if (tid==0){ u32 c=0; for(int r=0;r<=NSH;r++) c+=rlen[r]; count_s=c; }
  __syncthreads();
  u32 count = count_s;

  // ---- fallback rescan (correctness-only, never runs for bench data) ------
  if (count < (u32)k){
    const int nElem = c_N4[l]*4;
    float Tprev = Tl;
    for (int r=1; r<=7 && count<(u32)k; r++){
      float Tn = (r<7) ? (Tl - 1.5f*(float)r) : -3.0e38f;
      for (u32 i=tid; i<(u32)nElem; i+=1024u){
        float x = p[i];
        if (x>Tn && x<=Tprev){
          u32 pp = atomicAdd(&ocnt[l],1u);
          if (pp<OVCAP){ u32* d=cdO+(size_t)pp*2u; d[0]=__float_as_uint(x); d[1]=i; }
        }
      }
      __syncthreads();
      if (tid==0){
        rlen[NSH]=min(atomicAdd(&ocnt[l],0u),(u32)OVCAP);
        u32 c=0; for(int rr=0;rr<=NSH;rr++) c+=rlen[rr]; count_s=c;
      }
      __syncthreads();
      count = count_s;
      Tprev = Tn;
    }
  }

  if (count > (u32)k){
    // --- pass A: linear-quantized histogram ---
    const u32 rep = wave & 3u;
    for (int r=0;r<=NSH;r++){
      const u32* cdR = lvbase + ((r<NSH)?(size_t)r*SHCAP:(size_t)NSH*SHCAP)*2u;
      u32 len = rlen[r];
      for (u32 i=tid;i<len;i+=1024u)
        atomicAdd(&lhist[rep][qbin(cdR[2*(size_t)i],Tl)], 1u);
    }
    __syncthreads();
    // merge replicas: thread owns bins [tid*4, tid*4+4)
    u32 base = tid*4u;
    u32 hb[4]; u32 ls=0u;
#pragma unroll
    for (int b2_=0;b2_<4;b2_++){
      u32 h = lhist[0][base+(u32)b2_]+lhist[1][base+(u32)b2_]
            + lhist[2][base+(u32)b2_]+lhist[3][base+(u32)b2_];
      hb[b2_]=h; ls+=h;
    }
    // suffix-scan across threads (descending bin index)
    u32 x = ls;
#pragma unroll
    for (int off=1; off<64; off<<=1){
      u32 y = __shfl_down(x, off, 64);
      if (lane + (u32)off < 64u) x += y;
    }
    if (lane==0u) sufw[wave]=x;
    __syncthreads();
    u32 wsuf=0u;
    for (u32 w=wave+1u;w<16u;w++) wsuf += sufw[w];
    u32 suffix_after = wsuf + (x - ls);  // strictly above my 4-bin chunk
    if (suffix_after < (u32)k && (u32)k <= suffix_after + ls){
      u32 run = suffix_after;
      for (int b2_=3;b2_>=0;b2_--){
        u32 h = hb[b2_];
        run += h;
        if (run >= (u32)k){ c0_s = base+(u32)b2_; kk_s = (u32)k - (run - h); break; }
      }
    }
    __syncthreads();
    const u32 c0 = c0_s, kk = kk_s;

    // --- pass B: emit definite winners, stash tie-bin ---
    for (int r=0;r<=NSH;r++){
      const u32* cdR = lvbase + ((r<NSH)?(size_t)r*SHCAP:(size_t)NSH*SHCAP)*2u;
      u32 len = rlen[r];
      u32 iters = (len + 1023u)/1024u;
      for (u32 it=0; it<iters; it++){
        u32 i = it*1024u + tid;
        bool in = i < len;
        u32 bits = in ? cdR[2*(size_t)i] : 0u;
        u32 idx  = in ? cdR[2*(size_t)i+1] : 0u;
        u32 h    = qbin(bits,Tl);
        bool hi  = in && (h > c0);
        bool tie = in && (h == c0);
        u32 s = wave_alloc(&emit_s, hi);
        if (hi && s < (u32)k)
          emit_record(l,(int)s,bits,idx,boxp,keyA,rawbA,offbA,labA,svalA,validA);
        u32 t = wave_alloc(&ntie_s, tie);
        if (tie && t < (u32)TIE_CAP){ tb[t]=bits; ti[t]=idx; }
      }
    }
    __syncthreads();

    u32 nt = ntie_s;
    if (nt <= (u32)TIE_CAP){
      // --- exact refine within tie bin (full key desc, idx asc) ---
      for (u32 e=tid;e<nt;e+=1024u){
        u32 mk = okey(tb[e]); u32 mi = ti[e];
        u32 r=0u;
        for (u32 e2=0;e2<nt;e2++){
          u32 k2 = okey(tb[e2]);
          r += (k2>mk || (k2==mk && ti[e2]<mi)) ? 1u : 0u;
        }
        if (r < kk){
          u32 s = atomicAdd(&emit_s,1u);
          if (s < (u32)k)
            emit_record(l,(int)s,tb[e],mi,boxp,keyA,rawbA,offbA,labA,svalA,validA);
        }
      }
    } else {
      // --- degenerate tie overflow: exact streaming refine (correctness) ---
      for (int r=0;r<=NSH;r++){
        const u32* cdR = lvbase + ((r<NSH)?(size_t)r*SHCAP:(size_t)NSH*SHCAP)*2u;
        u32 len = rlen[r];
        for (u32 i=tid;i<len;i+=1024u){
          u32 bits=cdR[2*(size_t)i], idx=cdR[2*(size_t)i+1];
          if (qbin(bits,Tl)!=c0) continue;
          u32 mk=okey(bits); u32 rank=0u;
          for (int r2=0;r2<=NSH;r2++){
            const u32* c2 = lvbase + ((r2<NSH)?(size_t)r2*SHCAP:(size_t)NSH*SHCAP)*2u;
            u32 len2 = rlen[r2];
            for (u32 j=0;j<len2;j++){
              u32 b2=c2[2*(size_t)j];
              if (qbin(b2,Tl)!=c0) continue;
              u32 k2=okey(b2);
              rank += (k2>mk || (k2==mk && c2[2*(size_t)j+1]<idx)) ? 1u : 0u;
            }
          }
          if (rank<kk){
            u32 s=atomicAdd(&emit_s,1u);
            if (s<(u32)k)
              emit_record(l,(int)s,bits,idx,boxp,keyA,rawbA,offbA,labA,svalA,validA);
          }
        }
      }
    }
  } else {
    // count <= k: emit everything we have
    for (int r=0;r<=NSH;r++){
      const u32* cdR = lvbase + ((r<NSH)?(size_t)r*SHCAP:(size_t)NSH*SHCAP)*2u;
      u32 len = rlen[r];
      u32 iters = (len + 1023u)/1024u;
      for (u32 it=0; it<iters; it++){
        u32 i = it*1024u + tid;
        bool in = i < len;
        u32 bits = in ? cdR[2*(size_t)i] : 0u;
        u32 idx  = in ? cdR[2*(size_t)i+1] : 0u;
        u32 s = wave_alloc(&emit_s, in);
        if (in && s < (u32)k)
          emit_record(l,(int)s,bits,idx,boxp,keyA,rawbA,offbA,labA,svalA,validA);
      }
    }
  }
  __syncthreads();
  u32 em = min(emit_s,(u32)k);
  for (u32 i=em+tid;i<(u32)k;i+=1024u)
    emit_dummy(l,(int)i,keyA,rawbA,offbA,labA,svalA,validA);
}

// ------- global sort via rank-by-counting (unique keys) + fused gather -----
__global__ void __launch_bounds__(256)
k_rank(const u64* __restrict__ keyA,
       const float4* __restrict__ rawbA, const float4* __restrict__ offbA,
       const u32* __restrict__ labA, const float* __restrict__ svalA,
       const u32* __restrict__ validA,
       float4* srawb, float4* soffb, u32* slab, float* ssval, u32* svalid)
{
  __shared__ u64 sk[M_TOT];
  __shared__ u32 part[3][64];
  for (int i=threadIdx.x;i<M_TOT;i+=256) sk[i]=keyA[i];
  __syncthreads();
  int lane = threadIdx.x & 63;
  int wave = threadIdx.x >> 6;
  int i = blockIdx.x*64 + lane;
  u64 mk = sk[(i<M_TOT)?i:0];
  int j0 = wave*1225;
  u32 r=0;
#pragma unroll 5
  for (int j=j0;j<j0+1225;j++) r += (sk[j]>mk)?1u:0u;
  if (wave) part[wave-1][lane]=r;
  __syncthreads();
  if (wave==0 && i<M_TOT){
    r += part[0][lane]+part[1][lane]+part[2][lane];
    srawb[r]=rawbA[i]; soffb[r]=offbA[i]; slab[r]=labA[i];
    ssval[r]=svalA[i]; svalid[r]=validA[i];
  }
}

// ------- predecessor bitmask matrix: triangular 64x64 tiles + haspred ------
__global__ void __launch_bounds__(256)
k_cmat(const float4* __restrict__ soffb, u64* __restrict__ cmat,
       u64* __restrict__ haspred)
{
#pragma clang fp contract(off)
  int bi = blockIdx.x;
  int jt = (int)((sqrtf(8.0f*(float)bi+1.0f)-1.0f)*0.5f);
  while ((jt+1)*(jt+2)/2 <= bi) jt++;
  while (jt*(jt+1)/2 > bi) jt--;
  int wt = bi - jt*(jt+1)/2;

  __shared__ float rx[64],ry[64],rz[64],rw[64],ra[64];
  __shared__ float cx[64],cy[64],cz[64],cw[64],cae[64];
  int tid = threadIdx.x;
  if (tid<64){
    float4 b = soffb[wt*64+tid];
    rx[tid]=b.x; ry[tid]=b.y; rz[tid]=b.z; rw[tid]=b.w;
    ra[tid]=fmaxf(b.z-b.x,0.0f)*fmaxf(b.w-b.y,0.0f);
  } else if (tid<128){
    int c=tid-64;
    float4 b = soffb[jt*64+c];
    cx[c]=b.x; cy[c]=b.y; cz[c]=b.z; cw[c]=b.w;
    cae[c]=fmaxf(b.z-b.x,0.0f)*fmaxf(b.w-b.y,0.0f);
  }
  __syncthreads();
  int lane = tid & 63;
  int wave = tid >> 6;
  int rowg = wt*64 + lane;
  float bx=rx[lane], by=ry[lane], bz=rz[lane], bw=rw[lane], bar=ra[lane];
  for (int cc=wave*16; cc<wave*16+16; cc++){
    int jg = jt*64 + cc;
    if (jg >= M_TOT) continue;          // uniform across wave
    float jx=cx[cc], jy=cy[cc], jz=cz[cc], jw=cw[cc], jar=cae[cc];
    float ltx=fmaxf(bx,jx), lty=fmaxf(by,jy);
    float rbx=fminf(bz,jz), rby=fminf(bw,jw);
    float wx=fmaxf(rbx-ltx,0.0f), wy=fmaxf(rby-lty,0.0f);
    float inter=wx*wy;
    float iou = inter/(bar+jar-inter+1e-9f);
    bool bit = (rowg < jg) && (iou > 0.6f);
    u64 word = __ballot(bit);
    if (lane==0){
      cmat[(size_t)jg*CSTRIDE + (size_t)wt] = word;
      if (word) atomicOr(&haspred[jg>>6], 1ull<<(jg&63));
    }
  }
}

// ------- greedy resolution: only nodes WITH predecessors are sequential ----
__global__ void __launch_bounds__(256)
k_resolve(const u64* __restrict__ cmat, const u32* __restrict__ svalid,
          const u64* __restrict__ haspred, u64* __restrict__ kept)
{
  __shared__ u64 k0[NWORDS];            // decided-kept words (later += undec kept)
  __shared__ u64 uw[NWORDS];            // undecided (valid & haspred) words
  __shared__ u32 ubase[NWORDS];         // rank base per word
  __shared__ unsigned short ulist[UCAP];
  __shared__ u64 pmask[UCAP][2];        // compact undec-pred masks
  __shared__ u32 dhit[UCAP];
  __shared__ u32 nu_s;
  const u32 tid=threadIdx.x, lane=tid&63u, wave=tid>>6;

  for (u32 w=wave; w<NWORDS; w+=4){
    int j = (int)(w*64u+lane);
    u32 sv = (j<M_TOT)? svalid[j] : 0u;
    u64 hp = haspred[w];
    bool hpb = (hp>>lane)&1ull;
    u64 keepb = __ballot(sv && !hpb);
    u64 undb  = __ballot(sv && hpb);
    if (lane==0){ k0[w]=keepb; uw[w]=undb; }
  }
  __syncthreads();
  if (tid==0){
    u32 n=0;
    for (int w=0;w<NWORDS;w++){
      ubase[w]=n;
      u64 U=uw[w];
      while(U){ int b=__builtin_ctzll(U); U&=U-1ull;
                if (n<UCAP) ulist[n]=(unsigned short)(w*64+b); n++; }
    }
    nu_s=n;
  }
  __syncthreads();
  u32 nu = nu_s;

  if (nu>0u && nu<=UCAP){
    for (u32 t=tid; t<nu; t+=256u){
      u32 j = (u32)ulist[t];
      const u64* row = cmat + (size_t)j*CSTRIDE;
      u32 wmax = j>>6;
      u64 hit=0ull, pm0=0ull, pm1=0ull;
      for (u32 w=0; w<=wmax; w++){
        u64 rw = row[w];
        hit |= rw & k0[w];
        u64 ub = rw & uw[w];
        while(ub){
          int b=__builtin_ctzll(ub); ub&=ub-1ull;
          u32 idx = ubase[w] + (u32)__popcll(uw[w] & ((b==0)?0ull:((1ull<<b)-1ull)));
          if (idx<64u) pm0 |= 1ull<<idx; else pm1 |= 1ull<<(idx-64u);
        }
      }
      dhit[t] = (hit!=0ull)?1u:0u;
      pmask[t][0]=pm0; pmask[t][1]=pm1;
    }
    __syncthreads();
    if (tid==0){
      u64 ku0=0ull, ku1=0ull;
      for (u32 t=0;t<nu;t++){
        bool sup = dhit[t] || ((pmask[t][0]&ku0)|(pmask[t][1]&ku1))!=0ull;
        if (!sup){
          if (t<64u) ku0|=1ull<<t; else ku1|=1ull<<(t-64u);
          u32 j=(u32)ulist[t];
          k0[j>>6] |= 1ull<<(j&63u);
        }
      }
    }
    __syncthreads();
  } else if (nu>UCAP){
    // exact slow path (never triggers for bench data)
    if (tid==0){
      for (int w=0;w<NWORDS;w++){
        u64 U=uw[w];
        while(U){
          int b=__builtin_ctzll(U); U&=U-1ull;
          u32 j=(u32)(w*64+b);
          const u64* row = cmat + (size_t)j*CSTRIDE;
          u64 hit=0ull; u32 wmax=j>>6;
          for (u32 w2=0;w2<=wmax;w2++) hit |= row[w2] & k0[w2];
          if (hit==0ull) k0[j>>6] |= 1ull<<(j&63u);
        }
      }
    }
    __syncthreads();
  }
  for (u32 w=tid; w<NWORDS; w+=256u) kept[w]=k0[w];
}

// ---------------- final outputs -------------------------------------------
__global__ void k_out(const u64* __restrict__ kept, const float4* __restrict__ srawb,
                      const float* __restrict__ ssval, const u32* __restrict__ slab,
                      float* __restrict__ out)
{
  int t=blockIdx.x*blockDim.x+threadIdx.x;
  if (t<M_TOT){
    u32 kb=(u32)((kept[t>>6]>>(t&63))&1ull);
    float kf=kb?1.0f:0.0f;
    float4 b=srawb[t];
    out[4*t+0]=fminf(fmaxf(b.x/1280.0f,0.0f),1.0f)*kf;
    out[4*t+1]=fminf(fmaxf(b.y/1280.0f,0.0f),1.0f)*kf;
    out[4*t+2]=fminf(fmaxf(b.z/1280.0f,0.0f),1.0f)*kf;
    out[4*t+3]=fminf(fmaxf(b.w/1280.0f,0.0f),1.0f)*kf;
    out[19600+t]=ssval[t]*kf;
    out[24500+t]=(float)slab[t];
    out[29400+t]=kf;
  }
}

// ---------------- host ----------------------------------------------------
extern "C" void kernel_launch(void* const* d_in, const int* in_sizes, int n_in,
                              void* d_out, int out_size, void* d_ws, size_t ws_size,
                              hipStream_t stream)
{
  const float* cls[5]={nullptr,nullptr,nullptr,nullptr,nullptr};
  const float* box[5]={nullptr,nullptr,nullptr,nullptr,nullptr};
  static const int clsEl[5]={18432000,4608000,1152000,288000,72000};
  static const int boxEl[5]={921600,230400,57600,14400,3600};
  for (int i=0;i<n_in;i++){
    int sz=in_sizes[i];
    bool done=false;
    for (int l=0;l<5 && !done;l++){
      if (sz==clsEl[l] && !cls[l]){ cls[l]=(const float*)d_in[i]; done=true; }
      else if (sz==boxEl[l] && !box[l]){ box[l]=(const float*)d_in[i]; done=true; }
    }
  }
  unsigned char* ws=(unsigned char*)d_ws;
  u32* cnt   = (u32*)(ws+OFF_CNT);
  u32* ocnt  = (u32*)(ws+OFF_OCNT);
  u64* kept  = (u64*)(ws+OFF_KEPT);
  u64* hpred = (u64*)(ws+OFF_HPRED);
  u32* cand  = (u32*)(ws+OFF_CAND);
  u64* keyA  = (u64*)(ws+OFF_KEY);
  float4* rawbA=(float4*)(ws+OFF_RAWB);
  float4* offbA=(float4*)(ws+OFF_OFFB);
  u32* labA  = (u32*)(ws+OFF_LAB);
  float* svalA=(float*)(ws+OFF_SVAL);
  u32* validA=(u32*)(ws+OFF_VALID);
  float4* srawb=(float4*)(ws+OFF_SRAWB);
  float4* soffb=(float4*)(ws+OFF_SOFFB);
  u32* slab  = (u32*)(ws+OFF_SLAB);
  float* ssval=(float*)(ws+OFF_SSVAL);
  u32* svalid=(u32*)(ws+OFF_SVALID);
  u64* cmat  = (u64*)(ws+OFF_CMAT);
  float* out = (float*)d_out;

  hipMemsetAsync(ws, 0, ZERO_BYTES, stream);

  k_collect<<<dim3(NBLK),dim3(256),0,stream>>>(cls[0],cls[1],cls[2],cls[3],cls[4],cnt,ocnt,cand);

  k_select<<<dim3(5),dim3(1024),0,stream>>>(cnt,ocnt,cand,
      cls[0],cls[1],cls[2],cls[3],cls[4],
      (const float4*)box[0],(const float4*)box[1],(const float4*)box[2],
      (const float4*)box[3],(const float4*)box[4],
      keyA,rawbA,offbA,labA,svalA,validA);

  k_rank  <<<dim3(77),dim3(256),0,stream>>>(keyA,rawbA,offbA,labA,svalA,validA,
                                            srawb,soffb,slab,ssval,svalid);
  k_cmat  <<<dim3(NBLK_CMAT),dim3(256),0,stream>>>(soffb,cmat,hpred);
  k_resolve<<<dim3(1),dim3(256),0,stream>>>(cmat,svalid,hpred,kept);
  k_out   <<<dim3(20),dim3(256),0,stream>>>(kept,srawb,ssval,slab,out);
}

// Round 8
// 238.693 us; speedup vs baseline: 1.7744x; 1.1958x over previous
//
#include <hip/hip_runtime.h>
#include <cmath>

typedef unsigned int u32;
typedef unsigned long long u64;

#define NLEV 5
#define M_TOT 4900
#define NWORDS 77          // ceil(4900/64)
#define CSTRIDE 80         // cmat row stride in u64 words (640B)
#define PAD_M 4928
#define NBLK 2999          // collect blocks (2048 float4 per block)
#define LDSQ 2048          // per-block LDS candidate queue
#define NSH 32             // flush-counter shards per level
#define SHCAP 2048         // entries per shard region
#define OVCAP 16384        // per-level overflow region entries
#define NREG 33            // 32 shards + overflow
#define LVST (NSH*SHCAP + OVCAP)   // entries per level region = 81920
#define TIE_CAP 4096
#define NBLK_CMAT 3003     // 77*78/2 triangular tiles
#define HBINS 4096         // linear-quantized histogram bins
#define UCAP 128           // max undecided nodes on the NMS fast path

__constant__ int   c_KLVL[5] = {1000,1000,1000,1000,900};
__constant__ int   c_LOFF[5] = {0,1000,2000,3000,4000};
__constant__ int   c_N4[5]   = {4608000,1152000,288000,72000,18000}; // float4s per level
__constant__ int   c_BB[6]   = {0,2250,2813,2954,2990,2999};         // block ranges per level
__constant__ float c_THR[5]  = {1.0f,0.65f,0.30f,-0.15f,-0.60f};

// ---- workspace layout (bytes) ----
constexpr size_t OFF_CNT   = 0;       // u32[5*NSH]
constexpr size_t OFF_OCNT  = 768;     // u32[8]
constexpr size_t OFF_KEPT  = 1024;    // u64[96]
constexpr size_t OFF_HPRED = 2048;    // u64[96]
constexpr size_t OFF_C0    = 2816;    // u32[5]
constexpr size_t OFF_KK    = 2848;    // u32[5]
constexpr size_t OFF_EMITC = 2880;    // u32[5]
constexpr size_t OFF_TIEC  = 2912;    // u32[5]
constexpr size_t OFF_GHIST = 4096;    // u32[5*HBINS]
constexpr size_t ZERO_BYTES= OFF_GHIST + (size_t)NLEV*HBINS*4;       // 86016
constexpr size_t OFF_TIEB  = ZERO_BYTES;                             // u32[5*TIE_CAP*2]
constexpr size_t OFF_CAND  = OFF_TIEB + (size_t)NLEV*TIE_CAP*8;      // u32[5*LVST*2]
constexpr size_t OFF_KEY   = OFF_CAND + (size_t)NLEV*LVST*8;         // u64[PAD_M]
constexpr size_t OFF_RAWB  = OFF_KEY   + (size_t)PAD_M*8;            // float4
constexpr size_t OFF_OFFB  = OFF_RAWB  + (size_t)PAD_M*16;
constexpr size_t OFF_LAB   = OFF_OFFB  + (size_t)PAD_M*16;           // u32
constexpr size_t OFF_SVAL  = OFF_LAB   + (size_t)PAD_M*4;            // f32
constexpr size_t OFF_VALID = OFF_SVAL  + (size_t)PAD_M*4;            // u32
constexpr size_t OFF_SRAWB = OFF_VALID + (size_t)PAD_M*4;            // float4
constexpr size_t OFF_SOFFB = OFF_SRAWB + (size_t)PAD_M*16;
constexpr size_t OFF_SLAB  = OFF_SOFFB + (size_t)PAD_M*16;           // u32
constexpr size_t OFF_SSVAL = OFF_SLAB  + (size_t)PAD_M*4;            // f32
constexpr size_t OFF_SVALID= OFF_SSVAL + (size_t)PAD_M*4;            // u32
constexpr size_t OFF_CMAT  = (OFF_SVALID + (size_t)PAD_M*4 + 255) & ~(size_t)255;

__device__ __forceinline__ u32 okey(u32 u){
  return (u & 0x80000000u) ? ~u : (u | 0x80000000u);
}

__device__ __forceinline__ u32 qbin(u32 bits, float T){
  float x = __uint_as_float(bits);
  int b = (int)((x - T)*800.0f);
  return (u32)max(0, min(HBINS-1, b));
}

__device__ __forceinline__ u32 lane_prior(u64 mask){
  return __builtin_amdgcn_mbcnt_hi((u32)(mask>>32),
         __builtin_amdgcn_mbcnt_lo((u32)mask, 0u));
}

// wave-aggregated LDS counter allocation; wave-uniform execution required.
__device__ __forceinline__ u32 wave_alloc(u32* ctr, bool take){
  u64 mask = __ballot(take);
  if (mask==0ull) return 0xFFFFFFFFu;
  u32 prior = lane_prior(mask);
  u32 total = (u32)__popcll(mask);
  int leader = __ffsll((unsigned long long)mask) - 1;
  u32 base = 0;
  if (take && prior==0u) base = atomicAdd(ctr, total);
  base = __shfl(base, leader, 64);
  return take ? (base + prior) : 0xFFFFFFFFu;
}

__device__ __forceinline__ const u32* region_ptr(u32* cand, int l, int r){
  return cand + ((size_t)l*LVST + ((r<NSH)?(size_t)r*SHCAP:(size_t)NSH*SHCAP))*2u;
}

// ---------------- candidate collection (pure streaming pass) --------------
__global__ void __launch_bounds__(256)
k_collect(const float* __restrict__ a0, const float* __restrict__ a1,
          const float* __restrict__ a2, const float* __restrict__ a3,
          const float* __restrict__ a4,
          u32* __restrict__ cnt, u32* __restrict__ ocnt, u32* __restrict__ cand)
{
  const int b = blockIdx.x;
  const int l = (b<c_BB[1])?0:(b<c_BB[2])?1:(b<c_BB[3])?2:(b<c_BB[4])?3:4;
  const float* __restrict__ p = (l==0)?a0:(l==1)?a1:(l==2)?a2:(l==3)?a3:a4;
  const float T = c_THR[l];
  const int n4l = c_N4[l];
  const int lb  = b - c_BB[l];
  const int shard = lb & (NSH-1);
  const int base4 = lb*2048 + (int)threadIdx.x;

  __shared__ u32 lcnt, gbase;
  __shared__ u32 lbitsA[LDSQ];
  __shared__ u32 lidxA[LDSQ];
  if (threadIdx.x==0) lcnt=0u;
  __syncthreads();

  float4 xs[8];
#pragma unroll
  for (int u=0;u<8;u++){
    int q = base4 + u*256;
    int qc = (q < n4l) ? q : (n4l-1);
    xs[u] = *(const float4*)(p + (size_t)qc*4u);
  }
  u32* cdS = cand + ((size_t)l*LVST + (size_t)shard*SHCAP)*2u;
  u32* cdO = cand + ((size_t)l*LVST + (size_t)NSH*SHCAP)*2u;
#pragma unroll
  for (int u=0;u<8;u++){
    int q = base4 + u*256;
    if (q < n4l){
      float v[4]={xs[u].x,xs[u].y,xs[u].z,xs[u].w};
#pragma unroll
      for (int i=0;i<4;i++){
        if (v[i] > T){
          u32 s = atomicAdd(&lcnt,1u);
          u32 bits = __float_as_uint(v[i]);
          u32 idx  = (u32)(q*4+i);
          if (s < LDSQ){ lbitsA[s]=bits; lidxA[s]=idx; }
          else {
            u32 pp = atomicAdd(&ocnt[l],1u);           // rare overflow spill
            if (pp < OVCAP){ u32* d=cdO+(size_t)pp*2u; d[0]=bits; d[1]=idx; }
          }
        }
      }
    }
  }
  __syncthreads();
  if (threadIdx.x==0){
    u32 m = min(lcnt,(u32)LDSQ);
    gbase = (m>0u) ? atomicAdd(&cnt[l*NSH+shard],m) : 0xFFFFFFFFu;
  }
  __syncthreads();
  u32 m = min(lcnt,(u32)LDSQ);
  for (u32 i=threadIdx.x;i<m;i+=256u){
    u32 pp = gbase + i;
    if (pp < SHCAP){ u32* d=cdS+(size_t)pp*2u; d[0]=lbitsA[i]; d[1]=lidxA[i]; }
    else {
      u32 q = atomicAdd(&ocnt[l],1u);                  // shard-full spill (rare)
      if (q < OVCAP){ u32* d=cdO+(size_t)q*2u; d[0]=lbitsA[i]; d[1]=lidxA[i]; }
    }
  }
}

// ------------- per-region LDS histogram -> global merge (wide) -------------
__global__ void __launch_bounds__(256)
k_hist(const u32* __restrict__ cnt, const u32* __restrict__ ocnt,
       u32* __restrict__ cand, u32* __restrict__ ghist)
{
  const int l = blockIdx.x / NREG;
  const int r = blockIdx.x % NREG;
  const u32 len = (r<NSH) ? min(cnt[l*NSH+r],(u32)SHCAP) : min(ocnt[l],(u32)OVCAP);
  __shared__ u32 lh[HBINS];
  for (u32 i=threadIdx.x;i<(u32)HBINS;i+=256u) lh[i]=0u;
  __syncthreads();
  if (len){
    const u32* cdR = region_ptr(cand,l,r);
    const float Tl = c_THR[l];
    for (u32 i=threadIdx.x;i<len;i+=256u)
      atomicAdd(&lh[qbin(cdR[2*(size_t)i],Tl)],1u);
  }
  __syncthreads();
  u32* gh = ghist + (u32)l*HBINS;
  for (u32 i=threadIdx.x;i<(u32)HBINS;i+=256u){
    u32 v=lh[i];
    if (v) atomicAdd(&gh[i],v);
  }
}

// ------------- cutoff from global histogram (+ correctness fallback) -------
__global__ void __launch_bounds__(1024)
k_cut(u32* __restrict__ cnt, u32* __restrict__ ocnt, u32* __restrict__ cand,
      u32* __restrict__ ghist,
      const float* __restrict__ a0, const float* __restrict__ a1,
      const float* __restrict__ a2, const float* __restrict__ a3,
      const float* __restrict__ a4,
      u32* __restrict__ c0A, u32* __restrict__ kkA)
{
  const int l = blockIdx.x;
  const int k = c_KLVL[l];
  const float Tl = c_THR[l];
  const float* __restrict__ p = (l==0)?a0:(l==1)?a1:(l==2)?a2:(l==3)?a3:a4;
  u32* cdO = cand + ((size_t)l*LVST + (size_t)NSH*SHCAP)*2u;
  u32* gh = ghist + (u32)l*HBINS;

  __shared__ u32 rlen[NREG];
  __shared__ u32 count_s, sufw[16];
  __shared__ u32 c0_s, kk_s;
  const u32 tid=threadIdx.x, lane=tid&63u, wave=tid>>6;
  if (tid<NSH) rlen[tid]=min(cnt[l*NSH+tid],(u32)SHCAP);
  if (tid==NSH) rlen[NSH]=min(ocnt[l],(u32)OVCAP);
  if (tid==0){ c0_s=0u; kk_s=(u32)k; }
  __syncthreads();
  if (tid==0){ u32 c=0; for(int r=0;r<NREG;r++) c+=rlen[r]; count_s=c; }
  __syncthreads();
  u32 count = count_s;

  // fallback rescan (correctness-only; never runs for bench data)
  if (count < (u32)k){
    const int nElem = c_N4[l]*4;
    float Tprev = Tl;
    u32 oc0 = rlen[NSH];
    for (int r=1; r<=7 && count<(u32)k; r++){
      float Tn = (r<7) ? (Tl - 1.5f*(float)r) : -3.0e38f;
      for (u32 i=tid; i<(u32)nElem; i+=1024u){
        float x = p[i];
        if (x>Tn && x<=Tprev){
          u32 pp = atomicAdd(&ocnt[l],1u);
          if (pp<OVCAP){ u32* d=cdO+(size_t)pp*2u; d[0]=__float_as_uint(x); d[1]=i; }
        }
      }
      __syncthreads();
      if (tid==0){
        rlen[NSH]=min(atomicAdd(&ocnt[l],0u),(u32)OVCAP);
        u32 c=0; for(int rr=0;rr<NREG;rr++) c+=rlen[rr]; count_s=c;
      }
      __syncthreads();
      count = count_s;
      Tprev = Tn;
    }
    if (tid==0 && rlen[NSH]>oc0) atomicAdd(&gh[0], rlen[NSH]-oc0); // all new in bin 0
    __syncthreads();
  }

  if (count > (u32)k){
    u32 base = tid*4u;
    u32 hb[4]; u32 ls=0u;
#pragma unroll
    for (int b2_=0;b2_<4;b2_++){ u32 h=gh[base+(u32)b2_]; hb[b2_]=h; ls+=h; }
    u32 x = ls;
#pragma unroll
    for (int off=1; off<64; off<<=1){
      u32 y = __shfl_down(x, off, 64);
      if (lane + (u32)off < 64u) x += y;
    }
    if (lane==0u) sufw[wave]=x;
    __syncthreads();
    u32 wsuf=0u;
    for (u32 w=wave+1u;w<16u;w++) wsuf += sufw[w];
    u32 suffix_after = wsuf + (x - ls);
    if (suffix_after < (u32)k && (u32)k <= suffix_after + ls){
      u32 run = suffix_after;
      for (int b2_=3;b2_>=0;b2_--){
        u32 h = hb[b2_];
        run += h;
        if (run >= (u32)k){ c0_s = base+(u32)b2_; kk_s = (u32)k - (run - h); break; }
      }
    }
    __syncthreads();
  }
  if (tid==0){ c0A[l]=c0_s; kkA[l]=kk_s; }
}

// ---------------- record emit helpers --------------------------------------
__device__ __forceinline__ void emit_record(int l, int slot, u32 lbits, u32 idx,
    const float4* __restrict__ boxp, u64* keyA, float4* rawbA, float4* offbA,
    u32* labA, float* svalA, u32* validA)
{
#pragma clang fp contract(off)
  float x = __uint_as_float(lbits);
  float s = (float)(1.0 / (1.0 + exp(-(double)x)));
  u32 valid = (s > 0.05f) ? 1u : 0u;
  u32 label = idx % 80u;
  u32 anchor = idx / 80u;
  float4 bx = boxp[anchor];
  float off = (float)label * 1281.0f;   // label * (IMG + 1)
  float4 ob;
  ob.x = bx.x + off; ob.y = bx.y + off; ob.z = bx.z + off; ob.w = bx.w + off;
  u32 pos = ((u32)l << 25) | idx;
  u32 khi = valid ? okey(lbits) : 0u;
  int g = c_LOFF[l] + slot;
  keyA[g]  = ((u64)khi << 32) | (u64)(u32)(~pos);
  rawbA[g] = bx; offbA[g] = ob; labA[g] = label;
  svalA[g] = valid ? s : 0.0f; validA[g] = valid;
}

__device__ __forceinline__ void emit_dummy(int l, int slot,
    u64* keyA, float4* rawbA, float4* offbA, u32* labA, float* svalA, u32* validA)
{
  u32 pos = ((u32)l<<25) | (0x1FFFFFFu - (u32)slot);  // unique, beyond real idx
  int g = c_LOFF[l]+slot;
  float4 z; z.x=z.y=z.z=z.w=0.0f;
  keyA[g]=(u64)(u32)(~pos);
  rawbA[g]=z; offbA[g]=z; labA[g]=0u; svalA[g]=0.0f; validA[g]=0u;
}

// ------------- wide emit: winners + tie staging per region -----------------
__global__ void __launch_bounds__(256)
k_emit(const u32* __restrict__ cnt, const u32* __restrict__ ocnt,
       u32* __restrict__ cand,
       const u32* __restrict__ c0A,
       u32* __restrict__ emitc, u32* __restrict__ tiec, u32* __restrict__ tieb,
       const float4* b0, const float4* b1, const float4* b2,
       const float4* b3, const float4* b4,
       u64* keyA, float4* rawbA, float4* offbA,
       u32* labA, float* svalA, u32* validA)
{
  const int l = blockIdx.x / NREG;
  const int r = blockIdx.x % NREG;
  const u32 len = (r<NSH) ? min(cnt[l*NSH+r],(u32)SHCAP) : min(ocnt[l],(u32)OVCAP);
  if (len==0u) return;
  const float4* boxp = (l==0)?b0:(l==1)?b1:(l==2)?b2:(l==3)?b3:b4;
  const u32* cdR = region_ptr(cand,l,r);
  const float Tl = c_THR[l];
  const u32 c0 = c0A[l];
  const int k = c_KLVL[l];
  u32* tbL = tieb + (size_t)l*TIE_CAP*2u;

  __shared__ u32 wb[1024], wi[1024], tb2[1024], ti2[1024];
  __shared__ u32 nw_s, nt_s, gb_s, tgb_s;
  const u32 tid=threadIdx.x;
  if (tid==0){ nw_s=0u; nt_s=0u; }
  __syncthreads();

  u32 iters=(len+255u)/256u;
  for (u32 it=0; it<iters; it++){
    u32 i = it*256u + tid;
    bool in = i < len;
    u32 bits = in ? cdR[2*(size_t)i] : 0u;
    u32 idx  = in ? cdR[2*(size_t)i+1] : 0u;
    u32 h    = in ? qbin(bits,Tl) : 0u;
    bool hi  = in && (h > c0);
    bool tie = in && (h == c0);
    u32 s = wave_alloc(&nw_s, hi);
    if (hi && s<1024u){ wb[s]=bits; wi[s]=idx; }
    u32 t = wave_alloc(&nt_s, tie);
    if (tie){
      if (t<1024u){ tb2[t]=bits; ti2[t]=idx; }
      else {
        u32 g=atomicAdd(&tiec[l],1u);                   // rare spill
        if (g<(u32)TIE_CAP){ tbL[2u*g]=bits; tbL[2u*g+1u]=idx; }
      }
    }
  }
  __syncthreads();
  u32 nw = min(nw_s,1024u), nt = min(nt_s,1024u);
  if (tid==0){
    gb_s  = nw ? atomicAdd(&emitc[l], nw) : 0u;
    tgb_s = nt ? atomicAdd(&tiec[l], nt) : 0u;
  }
  __syncthreads();
  for (u32 i=tid;i<nw;i+=256u){
    u32 slot = gb_s + i;
    if ((int)slot < k)
      emit_record(l,(int)slot,wb[i],wi[i],boxp,keyA,rawbA,offbA,labA,svalA,validA);
  }
  for (u32 i=tid;i<nt;i+=256u){
    u32 g = tgb_s + i;
    if (g<(u32)TIE_CAP){ tbL[2u*g]=tb2[i]; tbL[2u*g+1u]=ti2[i]; }
  }
}

// ------------- tie refine + dummy fill (small exact) -----------------------
__global__ void __launch_bounds__(1024)
k_tie(const u32* __restrict__ cnt, const u32* __restrict__ ocnt,
      u32* __restrict__ cand,
      const u32* __restrict__ c0A, const u32* __restrict__ kkA,
      u32* __restrict__ emitc, const u32* __restrict__ tiec,
      const u32* __restrict__ tieb,
      const float4* b0, const float4* b1, const float4* b2,
      const float4* b3, const float4* b4,
      u64* keyA, float4* rawbA, float4* offbA,
      u32* labA, float* svalA, u32* validA)
{
  const int l = blockIdx.x;
  const float4* boxp = (l==0)?b0:(l==1)?b1:(l==2)?b2:(l==3)?b3:b4;
  const int k = c_KLVL[l];
  const u32 kk = kkA[l];
  const u32 c0 = c0A[l];
  const float Tl = c_THR[l];
  const u32* tbL = tieb + (size_t)l*TIE_CAP*2u;
  const u32 ntg = tiec[l];
  const u32 tid = threadIdx.x;

  __shared__ u32 tb[TIE_CAP], ti[TIE_CAP];

  if (ntg <= (u32)TIE_CAP){
    for (u32 i=tid;i<ntg;i+=1024u){ tb[i]=tbL[2u*i]; ti[i]=tbL[2u*i+1u]; }
    __syncthreads();
    for (u32 e=tid;e<ntg;e+=1024u){
      u32 mk = okey(tb[e]); u32 mi = ti[e];
      u32 r=0u;
      for (u32 e2=0;e2<ntg;e2++){
        u32 k2 = okey(tb[e2]);
        r += (k2>mk || (k2==mk && ti[e2]<mi)) ? 1u : 0u;
      }
      if (r < kk){
        u32 s = atomicAdd(&emitc[l],1u);
        if ((int)s < k)
          emit_record(l,(int)s,tb[e],mi,boxp,keyA,rawbA,offbA,labA,svalA,validA);
      }
    }
  } else {
    // degenerate: exact streaming refine over regions (never for bench data)
    for (int r0=0;r0<NREG;r0++){
      const u32* cdR = region_ptr(cand,l,r0);
      u32 len = (r0<NSH)?min(cnt[l*NSH+r0],(u32)SHCAP):min(ocnt[l],(u32)OVCAP);
      for (u32 i=tid;i<len;i+=1024u){
        u32 bits=cdR[2*(size_t)i], idx=cdR[2*(size_t)i+1];
        if (qbin(bits,Tl)!=c0) continue;
        u32 mk=okey(bits); u32 rank=0u;
        for (int r2=0;r2<NREG;r2++){
          const u32* c2 = region_ptr(cand,l,r2);
          u32 len2 = (r2<NSH)?min(cnt[l*NSH+r2],(u32)SHCAP):min(ocnt[l],(u32)OVCAP);
          for (u32 j=0;j<len2;j++){
            u32 b2=c2[2*(size_t)j];
            if (qbin(b2,Tl)!=c0) continue;
            u32 k2=okey(b2);
            rank += (k2>mk || (k2==mk && c2[2*(size_t)j+1]<idx)) ? 1u : 0u;
          }
        }
        if (rank<kk){
          u32 s=atomicAdd(&emitc[l],1u);
          if ((int)s<k)
            emit_record(l,(int)s,bits,idx,boxp,keyA,rawbA,offbA,labA,svalA,validA);
        }
      }
    }
  }
  __syncthreads();
  __shared__ u32 em_s;
  if (tid==0) em_s = atomicAdd(&emitc[l],0u);
  __syncthreads();
  u32 em = min(em_s,(u32)k);
  for (u32 i=em+tid;i<(u32)k;i+=1024u)
    emit_dummy(l,(int)i,keyA,rawbA,offbA,labA,svalA,validA);
}

// ------- global sort via rank-by-counting (unique keys) + fused gather -----
__global__ void __launch_bounds__(256)
k_rank(const u64* __restrict__ keyA,
       const float4* __restrict__ rawbA, const float4* __restrict__ offbA,
       const u32* __restrict__ labA, const float* __restrict__ svalA,
       const u32* __restrict__ validA,
       float4* srawb, float4* soffb, u32* slab, float* ssval, u32* svalid)
{
  __shared__ u64 sk[M_TOT];
  __shared__ u32 part[3][64];
  for (int i=threadIdx.x;i<M_TOT;i+=256) sk[i]=keyA[i];
  __syncthreads();
  int lane = threadIdx.x & 63;
  int wave = threadIdx.x >> 6;
  int i = blockIdx.x*64 + lane;
  u64 mk = sk[(i<M_TOT)?i:0];
  int j0 = wave*1225;
  u32 r=0;
#pragma unroll 5
  for (int j=j0;j<j0+1225;j++) r += (sk[j]>mk)?1u:0u;
  if (wave) part[wave-1][lane]=r;
  __syncthreads();
  if (wave==0 && i<M_TOT){
    r += part[0][lane]+part[1][lane]+part[2][lane];
    srawb[r]=rawbA[i]; soffb[r]=offbA[i]; slab[r]=labA[i];
    ssval[r]=svalA[i]; svalid[r]=validA[i];
  }
}

// ------- predecessor bitmask matrix: triangular 64x64 tiles + haspred ------
__global__ void __launch_bounds__(256)
k_cmat(const float4* __restrict__ soffb, u64* __restrict__ cmat,
       u64* __restrict__ haspred)
{
#pragma clang fp contract(off)
  int bi = blockIdx.x;
  int jt = (int)((sqrtf(8.0f*(float)bi+1.0f)-1.0f)*0.5f);
  while ((jt+1)*(jt+2)/2 <= bi) jt++;
  while (jt*(jt+1)/2 > bi) jt--;
  int wt = bi - jt*(jt+1)/2;

  __shared__ float rx[64],ry[64],rz[64],rw[64],ra[64];
  __shared__ float cx[64],cy[64],cz[64],cw[64],cae[64];
  int tid = threadIdx.x;
  if (tid<64){
    float4 b = soffb[wt*64+tid];
    rx[tid]=b.x; ry[tid]=b.y; rz[tid]=b.z; rw[tid]=b.w;
    ra[tid]=fmaxf(b.z-b.x,0.0f)*fmaxf(b.w-b.y,0.0f);
  } else if (tid<128){
    int c=tid-64;
    float4 b = soffb[jt*64+c];
    cx[c]=b.x; cy[c]=b.y; cz[c]=b.z; cw[c]=b.w;
    cae[c]=fmaxf(b.z-b.x,0.0f)*fmaxf(b.w-b.y,0.0f);
  }
  __syncthreads();
  int lane = tid & 63;
  int wave = tid >> 6;
  int rowg = wt*64 + lane;
  float bx=rx[lane], by=ry[lane], bz=rz[lane], bw=rw[lane], bar=ra[lane];
  for (int cc=wave*16; cc<wave*16+16; cc++){
    int jg = jt*64 + cc;
    if (jg >= M_TOT) continue;          // uniform across wave
    float jx=cx[cc], jy=cy[cc], jz=cz[cc], jw=cw[cc], jar=cae[cc];
    float ltx=fmaxf(bx,jx), lty=fmaxf(by,jy);
    float rbx=fminf(bz,jz), rby=fminf(bw,jw);
    float wx=fmaxf(rbx-ltx,0.0f), wy=fmaxf(rby-lty,0.0f);
    float inter=wx*wy;
    float iou = inter/(bar+jar-inter+1e-9f);
    bool bit = (rowg < jg) && (iou > 0.6f);
    u64 word = __ballot(bit);
    if (lane==0){
      cmat[(size_t)jg*CSTRIDE + (size_t)wt] = word;
      if (word) atomicOr(&haspred[jg>>6], 1ull<<(jg&63));
    }
  }
}

// ------- greedy resolution: only nodes WITH predecessors are sequential ----
__global__ void __launch_bounds__(256)
k_resolve(const u64* __restrict__ cmat, const u32* __restrict__ svalid,
          const u64* __restrict__ haspred, u64* __restrict__ kept)
{
  __shared__ u64 k0[NWORDS];
  __shared__ u64 uw[NWORDS];
  __shared__ u32 ubase[NWORDS];
  __shared__ unsigned short ulist[UCAP];
  __shared__ u64 pmask[UCAP][2];
  __shared__ u32 dhit[UCAP];
  __shared__ u32 nu_s;
  const u32 tid=threadIdx.x, lane=tid&63u, wave=tid>>6;

  for (u32 w=wave; w<NWORDS; w+=4){
    int j = (int)(w*64u+lane);
    u32 sv = (j<M_TOT)? svalid[j] : 0u;
    u64 hp = haspred[w];
    bool hpb = (hp>>lane)&1ull;
    u64 keepb = __ballot(sv && !hpb);
    u64 undb  = __ballot(sv && hpb);
    if (lane==0){ k0[w]=keepb; uw[w]=undb; }
  }
  __syncthreads();
  if (tid==0){
    u32 n=0;
    for (int w=0;w<NWORDS;w++){
      ubase[w]=n;
      u64 U=uw[w];
      while(U){ int b=__builtin_ctzll(U); U&=U-1ull;
                if (n<UCAP) ulist[n]=(unsigned short)(w*64+b); n++; }
    }
    nu_s=n;
  }
  __syncthreads();
  u32 nu = nu_s;

  if (nu>0u && nu<=UCAP){
    for (u32 t=tid; t<nu; t+=256u){
      u32 j = (u32)ulist[t];
      const u64* row = cmat + (size_t)j*CSTRIDE;
      u32 wmax = j>>6;
      u64 hit=0ull, pm0=0ull, pm1=0ull;
      for (u32 w=0; w<=wmax; w++){
        u64 rw = row[w];
        hit |= rw & k0[w];
        u64 ub = rw & uw[w];
        while(ub){
          int b=__builtin_ctzll(ub); ub&=ub-1ull;
          u32 idx = ubase[w] + (u32)__popcll(uw[w] & ((b==0)?0ull:((1ull<<b)-1ull)));
          if (idx<64u) pm0 |= 1ull<<idx; else pm1 |= 1ull<<(idx-64u);
        }
      }
      dhit[t] = (hit!=0ull)?1u:0u;
      pmask[t][0]=pm0; pmask[t][1]=pm1;
    }
    __syncthreads();
    if (tid==0){
      u64 ku0=0ull, ku1=0ull;
      for (u32 t=0;t<nu;t++){
        bool sup = dhit[t] || ((pmask[t][0]&ku0)|(pmask[t][1]&ku1))!=0ull;
        if (!sup){
          if (t<64u) ku0|=1ull<<t; else ku1|=1ull<<(t-64u);
          u32 j=(u32)ulist[t];
          k0[j>>6] |= 1ull<<(j&63u);
        }
      }
    }
    __syncthreads();
  } else if (nu>UCAP){
    if (tid==0){
      for (int w=0;w<NWORDS;w++){
        u64 U=uw[w];
        while(U){
          int b=__builtin_ctzll(U); U&=U-1ull;
          u32 j=(u32)(w*64+b);
          const u64* row = cmat + (size_t)j*CSTRIDE;
          u64 hit=0ull; u32 wmax=j>>6;
          for (u32 w2=0;w2<=wmax;w2++) hit |= row[w2] & k0[w2];
          if (hit==0ull) k0[j>>6] |= 1ull<<(j&63u);
        }
      }
    }
    __syncthreads();
  }
  for (u32 w=tid; w<NWORDS; w+=256u) kept[w]=k0[w];
}

// ---------------- final outputs -------------------------------------------
__global__ void k_out(const u64* __restrict__ kept, const float4* __restrict__ srawb,
                      const float* __restrict__ ssval, const u32* __restrict__ slab,
                      float* __restrict__ out)
{
  int t=blockIdx.x*blockDim.x+threadIdx.x;
  if (t<M_TOT){
    u32 kb=(u32)((kept[t>>6]>>(t&63))&1ull);
    float kf=kb?1.0f:0.0f;
    float4 b=srawb[t];
    out[4*t+0]=fminf(fmaxf(b.x/1280.0f,0.0f),1.0f)*kf;
    out[4*t+1]=fminf(fmaxf(b.y/1280.0f,0.0f),1.0f)*kf;
    out[4*t+2]=fminf(fmaxf(b.z/1280.0f,0.0f),1.0f)*kf;
    out[4*t+3]=fminf(fmaxf(b.w/1280.0f,0.0f),1.0f)*kf;
    out[19600+t]=ssval[t]*kf;
    out[24500+t]=(float)slab[t];
    out[29400+t]=kf;
  }
}

// ---------------- host ----------------------------------------------------
extern "C" void kernel_launch(void* const* d_in, const int* in_sizes, int n_in,
                              void* d_out, int out_size, void* d_ws, size_t ws_size,
                              hipStream_t stream)
{
  const float* cls[5]={nullptr,nullptr,nullptr,nullptr,nullptr};
  const float* box[5]={nullptr,nullptr,nullptr,nullptr,nullptr};
  static const int clsEl[5]={18432000,4608000,1152000,288000,72000};
  static const int boxEl[5]={921600,230400,57600,14400,3600};
  for (int i=0;i<n_in;i++){
    int sz=in_sizes[i];
    bool done=false;
    for (int l=0;l<5 && !done;l++){
      if (sz==clsEl[l] && !cls[l]){ cls[l]=(const float*)d_in[i]; done=true; }
      else if (sz==boxEl[l] && !box[l]){ box[l]=(const float*)d_in[i]; done=true; }
    }
  }
  unsigned char* ws=(unsigned char*)d_ws;
  u32* cnt   = (u32*)(ws+OFF_CNT);
  u32* ocnt  = (u32*)(ws+OFF_OCNT);
  u64* kept  = (u64*)(ws+OFF_KEPT);
  u64* hpred = (u64*)(ws+OFF_HPRED);
  u32* c0A   = (u32*)(ws+OFF_C0);
  u32* kkA   = (u32*)(ws+OFF_KK);
  u32* emitc = (u32*)(ws+OFF_EMITC);
  u32* tiec  = (u32*)(ws+OFF_TIEC);
  u32* ghist = (u32*)(ws+OFF_GHIST);
  u32* tieb  = (u32*)(ws+OFF_TIEB);
  u32* cand  = (u32*)(ws+OFF_CAND);
  u64* keyA  = (u64*)(ws+OFF_KEY);
  float4* rawbA=(float4*)(ws+OFF_RAWB);
  float4* offbA=(float4*)(ws+OFF_OFFB);
  u32* labA  = (u32*)(ws+OFF_LAB);
  float* svalA=(float*)(ws+OFF_SVAL);
  u32* validA=(u32*)(ws+OFF_VALID);
  float4* srawb=(float4*)(ws+OFF_SRAWB);
  float4* soffb=(float4*)(ws+OFF_SOFFB);
  u32* slab  = (u32*)(ws+OFF_SLAB);
  float* ssval=(float*)(ws+OFF_SSVAL);
  u32* svalid=(u32*)(ws+OFF_SVALID);
  u64* cmat  = (u64*)(ws+OFF_CMAT);
  float* out = (float*)d_out;

  hipMemsetAsync(ws, 0, ZERO_BYTES, stream);

  k_collect<<<dim3(NBLK),dim3(256),0,stream>>>(cls[0],cls[1],cls[2],cls[3],cls[4],cnt,ocnt,cand);
  k_hist   <<<dim3(NLEV*NREG),dim3(256),0,stream>>>(cnt,ocnt,cand,ghist);
  k_cut    <<<dim3(NLEV),dim3(1024),0,stream>>>(cnt,ocnt,cand,ghist,
              cls[0],cls[1],cls[2],cls[3],cls[4],c0A,kkA);
  k_emit   <<<dim3(NLEV*NREG),dim3(256),0,stream>>>(cnt,ocnt,cand,c0A,emitc,tiec,tieb,
              (const float4*)box[0],(const float4*)box[1],(const float4*)box[2],
              (const float4*)box[3],(const float4*)box[4],
              keyA,rawbA,offbA,labA,svalA,validA);
  k_tie    <<<dim3(NLEV),dim3(1024),0,stream>>>(cnt,ocnt,cand,c0A,kkA,emitc,tiec,tieb,
              (const float4*)box[0],(const float4*)box[1],(const float4*)box[2],
              (const float4*)box[3],(const float4*)box[4],
              keyA,rawbA,offbA,labA,svalA,validA);
  k_rank   <<<dim3(77),dim3(256),0,stream>>>(keyA,rawbA,offbA,labA,svalA,validA,
                                             srawb,soffb,slab,ssval,svalid);
  k_cmat   <<<dim3(NBLK_CMAT),dim3(256),0,stream>>>(soffb,cmat,hpred);
  k_resolve<<<dim3(1),dim3(256),0,stream>>>(cmat,svalid,hpred,kept);
  k_out    <<<dim3(20),dim3(256),0,stream>>>(kept,srawb,ssval,slab,out);
}